// Round 1
// baseline (3360.470 us; speedup 1.0000x reference)
//
#include <hip/hip_runtime.h>

#define D 128
#define NG 256

// ---------------- Phase 1: edge scatter: agg[dst] += x[src] + edge_attr ----------------
// 32 threads per edge, each thread handles one float4 (4 of 128 cols).
__global__ __launch_bounds__(256) void scatter_edges_kernel(
    const float* __restrict__ x, const int* __restrict__ ei,
    const float* __restrict__ ea, float* __restrict__ agg, int E) {
  long long tid = (long long)blockIdx.x * blockDim.x + threadIdx.x;
  int e = (int)(tid >> 5);
  int c = (int)(tid & 31);
  if (e >= E) return;
  int s = ei[e];
  int d = ei[E + e];
  const float4* ea4 = (const float4*)ea;
  const float4* x4 = (const float4*)x;
  float4 m = ea4[(size_t)e * 32 + c];
  float4 xv = x4[(size_t)s * 32 + c];
  m.x += xv.x; m.y += xv.y; m.z += xv.z; m.w += xv.w;
  float* a = agg + (size_t)d * D + (size_t)c * 4;
  unsafeAtomicAdd(a + 0, m.x);
  unsafeAtomicAdd(a + 1, m.y);
  unsafeAtomicAdd(a + 2, m.z);
  unsafeAtomicAdd(a + 3, m.w);
}

// ---------------- Phase 2: per-graph node/cond counts ----------------
__global__ void counts_kernel(const int* __restrict__ batch, const int* __restrict__ primary,
                              int* __restrict__ ncount, int* __restrict__ ccnt, int N) {
  int n = blockIdx.x * blockDim.x + threadIdx.x;
  if (n >= N) return;
  int g = batch[n];
  atomicAdd(&ncount[g], 1);
  if (primary[n] == 0) atomicAdd(&ccnt[g], 1);
}

// ---------------- Phase 3: MLP h = relu((x+agg)@W1+b1)@W2+b2, in-place over agg;
// fused pooled-sum accumulation for condition nodes. 8 rows per 256-thread block.
__global__ __launch_bounds__(256) void mlp_kernel(
    const float* __restrict__ x, float* __restrict__ aggh,
    const float* __restrict__ W1, const float* __restrict__ b1,
    const float* __restrict__ W2, const float* __restrict__ b2,
    const int* __restrict__ batch, const int* __restrict__ primary,
    float* __restrict__ csum, int N) {
  __shared__ float y[8][D];
  __shared__ float t[8][D];
  int tid = threadIdx.x;
  int r = tid >> 5;
  int c4 = tid & 31;
  int base = blockIdx.x * 8;
  int n = base + r;

  // stage y = x + agg
  {
    float4 v = make_float4(0.f, 0.f, 0.f, 0.f);
    if (n < N) {
      float4 xv = ((const float4*)x)[(size_t)n * 32 + c4];
      float4 av = ((const float4*)aggh)[(size_t)n * 32 + c4];
      v = make_float4(xv.x + av.x, xv.y + av.y, xv.z + av.z, xv.w + av.w);
    }
    ((float4*)&y[r][0])[c4] = v;
  }
  __syncthreads();

  // GEMM1 + relu
  const float4* W1_4 = (const float4*)W1;
  float4 acc = ((const float4*)b1)[c4];
#pragma unroll 8
  for (int k = 0; k < D; ++k) {
    float yv = y[r][k];
    float4 w = W1_4[k * 32 + c4];
    acc.x += yv * w.x; acc.y += yv * w.y; acc.z += yv * w.z; acc.w += yv * w.w;
  }
  acc.x = acc.x > 0.f ? acc.x : 0.f;
  acc.y = acc.y > 0.f ? acc.y : 0.f;
  acc.z = acc.z > 0.f ? acc.z : 0.f;
  acc.w = acc.w > 0.f ? acc.w : 0.f;
  ((float4*)&t[r][0])[c4] = acc;
  __syncthreads();

  // GEMM2
  const float4* W2_4 = (const float4*)W2;
  float4 acc2 = ((const float4*)b2)[c4];
#pragma unroll 8
  for (int k = 0; k < D; ++k) {
    float tv = t[r][k];
    float4 w = W2_4[k * 32 + c4];
    acc2.x += tv * w.x; acc2.y += tv * w.y; acc2.z += tv * w.z; acc2.w += tv * w.w;
  }

  if (n < N) {
    ((float4*)aggh)[(size_t)n * 32 + c4] = acc2;  // h overwrites agg (row-local, safe)
    if (primary[n] == 0) {
      int g = batch[n];
      float* cs = csum + (size_t)g * D + (size_t)c4 * 4;
      unsafeAtomicAdd(cs + 0, acc2.x);
      unsafeAtomicAdd(cs + 1, acc2.y);
      unsafeAtomicAdd(cs + 2, acc2.z);
      unsafeAtomicAdd(cs + 3, acc2.w);
    }
  }
}

// ---------------- Phase 4: exclusive scan of graph sizes -> gstart ----------------
__global__ void scan_kernel(const int* __restrict__ ncount, int* __restrict__ gstart) {
  __shared__ int a[NG];
  int tx = threadIdx.x;
  int v = ncount[tx];
  a[tx] = v;
  __syncthreads();
  for (int off = 1; off < NG; off <<= 1) {
    int u = (tx >= off) ? a[tx - off] : 0;
    __syncthreads();
    a[tx] += u;
    __syncthreads();
  }
  gstart[tx] = a[tx] - v;
  if (tx == NG - 1) gstart[NG] = a[tx];
}

// ---------------- Phase 5: pool = csum / ccnt ----------------
__global__ void pool_kernel(const float* __restrict__ csum, const int* __restrict__ ccnt,
                            float* __restrict__ pool) {
  int g = blockIdx.x, c = threadIdx.x;
  int cnt = ccnt[g];
  pool[(size_t)g * D + c] = cnt > 0 ? csum[(size_t)g * D + c] / (float)cnt : 0.0f;
}

// ---------------- Phase 6: per-graph stable rank of primary nodes -> output row ----------------
__global__ __launch_bounds__(256) void rank_kernel(const int* __restrict__ primary,
                                                   const int* __restrict__ gstart,
                                                   int* __restrict__ pos) {
  int g = blockIdx.x;
  int s = gstart[g], e = gstart[g + 1];
  __shared__ int wcnt[4];
  int run = 0;
  for (int i0 = s; i0 < e; i0 += 256) {
    int n = i0 + threadIdx.x;
    bool valid = n < e;
    int isP = (valid && primary[n] == 1) ? 1 : 0;
    unsigned long long m = __ballot(isP);
    int lane = threadIdx.x & 63;
    int wid = threadIdx.x >> 6;
    if (lane == 0) wcnt[wid] = __popcll(m);
    __syncthreads();
    int pre = __popcll(m & ((1ULL << lane) - 1ULL));
    int woff = 0;
#pragma unroll
    for (int w = 0; w < 4; ++w)
      if (w < wid) woff += wcnt[w];
    int tot = wcnt[0] + wcnt[1] + wcnt[2] + wcnt[3];
    if (valid) pos[n] = isP ? (s + run + woff + pre) : -1;
    run += tot;
    __syncthreads();
  }
}

// ---------------- Phase 7: write out[pos] = [h | pool[g]] (wave per row) ----------------
__global__ __launch_bounds__(256) void write_kernel(
    const float* __restrict__ h, const float* __restrict__ pool,
    const int* __restrict__ batch, const int* __restrict__ pos,
    float* __restrict__ out, int N) {
  long long tid = (long long)blockIdx.x * blockDim.x + threadIdx.x;
  int n = (int)(tid >> 6);
  int c = (int)(tid & 63);
  if (n >= N) return;
  int p = pos[n];
  if (p < 0) return;
  float4 v;
  if (c < 32)
    v = ((const float4*)h)[(size_t)n * 32 + c];
  else
    v = ((const float4*)pool)[(size_t)batch[n] * 32 + (c - 32)];
  ((float4*)out)[(size_t)p * 64 + c] = v;
}

extern "C" void kernel_launch(void* const* d_in, const int* in_sizes, int n_in,
                              void* d_out, int out_size, void* d_ws, size_t ws_size,
                              hipStream_t stream) {
  const float* x = (const float*)d_in[0];
  const int* ei = (const int*)d_in[1];
  const float* ea = (const float*)d_in[2];
  const int* batch = (const int*)d_in[3];
  const int* primary = (const int*)d_in[4];
  const float* W1 = (const float*)d_in[5];
  const float* b1 = (const float*)d_in[6];
  const float* W2 = (const float*)d_in[7];
  const float* b2 = (const float*)d_in[8];
  float* out = (float*)d_out;

  const int N = in_sizes[0] / D;  // 100000
  const int E = in_sizes[1] / 2;  // 1600000

  // workspace layout
  float* agg = (float*)d_ws;                       // N*D (agg, then h in-place)
  float* csum = agg + (size_t)N * D;               // NG*D
  int* ccnt = (int*)(csum + (size_t)NG * D);       // NG
  int* ncount = ccnt + NG;                         // NG
  int* gstart = ncount + NG;                       // NG+1 (reserve 260 for alignment)
  float* pool = (float*)(gstart + 260);            // NG*D
  int* pos = (int*)(pool + (size_t)NG * D);        // N

  size_t zbytes = ((size_t)N * D + (size_t)NG * D) * 4 + (size_t)(NG + NG) * 4;
  hipMemsetAsync(d_ws, 0, zbytes, stream);
  hipMemsetAsync(d_out, 0, (size_t)out_size * 4, stream);

  {
    long long threads = (long long)E * 32;
    int blocks = (int)((threads + 255) / 256);
    scatter_edges_kernel<<<blocks, 256, 0, stream>>>(x, ei, ea, agg, E);
  }
  counts_kernel<<<(N + 255) / 256, 256, 0, stream>>>(batch, primary, ncount, ccnt, N);
  mlp_kernel<<<(N + 7) / 8, 256, 0, stream>>>(x, agg, W1, b1, W2, b2, batch, primary, csum, N);
  scan_kernel<<<1, NG, 0, stream>>>(ncount, gstart);
  pool_kernel<<<NG, D, 0, stream>>>(csum, ccnt, pool);
  rank_kernel<<<NG, 256, 0, stream>>>(primary, gstart, pos);
  write_kernel<<<(int)(((long long)N * 64 + 255) / 256), 256, 0, stream>>>(agg, pool, batch, pos, out, N);
}

// Round 2
// 1043.516 us; speedup vs baseline: 3.2203x; 3.2203x over previous
//
#include <hip/hip_runtime.h>

#define D 128
#define NG 256

// ---------------- CSR build: degree histogram ----------------
__global__ __launch_bounds__(256) void deg_kernel(const int* __restrict__ ei,
                                                  int* __restrict__ deg, int E) {
  int e = blockIdx.x * blockDim.x + threadIdx.x;
  if (e < E) atomicAdd(&deg[ei[E + e]], 1);
}

// ---------------- scan over N (3-phase) ----------------
__global__ __launch_bounds__(256) void scan_block_sums(const int* __restrict__ deg,
                                                       int* __restrict__ bsum, int N) {
  __shared__ int red[256];
  int t = threadIdx.x;
  int base = blockIdx.x * 1024;
  int s = 0;
#pragma unroll
  for (int j = 0; j < 4; ++j) {
    int i = base + t * 4 + j;
    if (i < N) s += deg[i];
  }
  red[t] = s;
  __syncthreads();
  for (int o = 128; o > 0; o >>= 1) {
    if (t < o) red[t] += red[t + o];
    __syncthreads();
  }
  if (t == 0) bsum[blockIdx.x] = red[0];
}

__global__ void scan_bsum(int* __restrict__ bsum, int nb) {
  if (threadIdx.x == 0) {
    int run = 0;
    for (int i = 0; i < nb; ++i) {
      int v = bsum[i];
      bsum[i] = run;
      run += v;
    }
  }
}

__global__ __launch_bounds__(256) void scan_final(const int* __restrict__ deg,
                                                  const int* __restrict__ bsum,
                                                  int* __restrict__ off, int N) {
  __shared__ int ts[256];
  int t = threadIdx.x;
  int base = blockIdx.x * 1024;
  int v[4];
  int s = 0;
#pragma unroll
  for (int j = 0; j < 4; ++j) {
    int i = base + t * 4 + j;
    v[j] = (i < N) ? deg[i] : 0;
    s += v[j];
  }
  ts[t] = s;
  __syncthreads();
  for (int o = 1; o < 256; o <<= 1) {
    int u = (t >= o) ? ts[t - o] : 0;
    __syncthreads();
    ts[t] += u;
    __syncthreads();
  }
  int excl = ts[t] - s + bsum[blockIdx.x];
#pragma unroll
  for (int j = 0; j < 4; ++j) {
    int i = base + t * 4 + j;
    if (i < N) off[i] = excl;
    excl += v[j];
    if (i == N - 1) off[N] = excl;
  }
}

// ---------------- CSR fill: csr[off[dst]+slot] = (src, e) ----------------
__global__ __launch_bounds__(256) void fill_kernel(const int* __restrict__ ei,
                                                   const int* __restrict__ off,
                                                   int* __restrict__ cursor,
                                                   int2* __restrict__ csr, int E) {
  int e = blockIdx.x * blockDim.x + threadIdx.x;
  if (e >= E) return;
  int d = ei[E + e];
  int slot = atomicAdd(&cursor[d], 1);
  csr[off[d] + slot] = make_int2(ei[e], e);
}

// ---------------- Gather: y[n] = x[n] + sum_{e:(s->n)} (x[s] + ea[e]) ----------------
// 32 threads per node, each owns one float4 column chunk.
__global__ __launch_bounds__(256) void gather_kernel(const float* __restrict__ x,
                                                     const float* __restrict__ ea,
                                                     const int2* __restrict__ csr,
                                                     const int* __restrict__ off,
                                                     float* __restrict__ y, int N) {
  long long tid = (long long)blockIdx.x * blockDim.x + threadIdx.x;
  int n = (int)(tid >> 5);
  int c = (int)(tid & 31);
  if (n >= N) return;
  const float4* x4 = (const float4*)x;
  const float4* ea4 = (const float4*)ea;
  float4 acc = x4[(size_t)n * 32 + c];
  int s = off[n], e = off[n + 1];
  for (int k = s; k < e; ++k) {
    int2 p = csr[k];
    float4 a = ea4[(size_t)p.y * 32 + c];
    float4 xv = x4[(size_t)p.x * 32 + c];
    acc.x += a.x + xv.x;
    acc.y += a.y + xv.y;
    acc.z += a.z + xv.z;
    acc.w += a.w + xv.w;
  }
  ((float4*)y)[(size_t)n * 32 + c] = acc;
}

// ---------------- per-graph node/cond counts ----------------
__global__ void counts_kernel(const int* __restrict__ batch, const int* __restrict__ primary,
                              int* __restrict__ ncount, int* __restrict__ ccnt, int N) {
  int n = blockIdx.x * blockDim.x + threadIdx.x;
  if (n >= N) return;
  int g = batch[n];
  atomicAdd(&ncount[g], 1);
  if (primary[n] == 0) atomicAdd(&ccnt[g], 1);
}

// ---------------- MLP h = relu(y@W1+b1)@W2+b2, in-place over y; fused cond-pool sum ----------------
__global__ __launch_bounds__(256) void mlp_kernel(
    float* __restrict__ y,
    const float* __restrict__ W1, const float* __restrict__ b1,
    const float* __restrict__ W2, const float* __restrict__ b2,
    const int* __restrict__ batch, const int* __restrict__ primary,
    float* __restrict__ csum, int N) {
  __shared__ float ys[8][D];
  __shared__ float ts[8][D];
  int tid = threadIdx.x;
  int r = tid >> 5;
  int c4 = tid & 31;
  int base = blockIdx.x * 8;
  int n = base + r;

  {
    float4 v = make_float4(0.f, 0.f, 0.f, 0.f);
    if (n < N) v = ((const float4*)y)[(size_t)n * 32 + c4];
    ((float4*)&ys[r][0])[c4] = v;
  }
  __syncthreads();

  const float4* W1_4 = (const float4*)W1;
  float4 acc = ((const float4*)b1)[c4];
#pragma unroll 8
  for (int k = 0; k < D; ++k) {
    float yv = ys[r][k];
    float4 w = W1_4[k * 32 + c4];
    acc.x += yv * w.x; acc.y += yv * w.y; acc.z += yv * w.z; acc.w += yv * w.w;
  }
  acc.x = acc.x > 0.f ? acc.x : 0.f;
  acc.y = acc.y > 0.f ? acc.y : 0.f;
  acc.z = acc.z > 0.f ? acc.z : 0.f;
  acc.w = acc.w > 0.f ? acc.w : 0.f;
  ((float4*)&ts[r][0])[c4] = acc;
  __syncthreads();

  const float4* W2_4 = (const float4*)W2;
  float4 acc2 = ((const float4*)b2)[c4];
#pragma unroll 8
  for (int k = 0; k < D; ++k) {
    float tv = ts[r][k];
    float4 w = W2_4[k * 32 + c4];
    acc2.x += tv * w.x; acc2.y += tv * w.y; acc2.z += tv * w.z; acc2.w += tv * w.w;
  }

  if (n < N) {
    ((float4*)y)[(size_t)n * 32 + c4] = acc2;  // h overwrites y (row-local, safe)
    if (primary[n] == 0) {
      int g = batch[n];
      float* cs = csum + (size_t)g * D + (size_t)c4 * 4;
      unsafeAtomicAdd(cs + 0, acc2.x);
      unsafeAtomicAdd(cs + 1, acc2.y);
      unsafeAtomicAdd(cs + 2, acc2.z);
      unsafeAtomicAdd(cs + 3, acc2.w);
    }
  }
}

// ---------------- exclusive scan of graph sizes -> gstart ----------------
__global__ void scan_kernel(const int* __restrict__ ncount, int* __restrict__ gstart) {
  __shared__ int a[NG];
  int tx = threadIdx.x;
  int v = ncount[tx];
  a[tx] = v;
  __syncthreads();
  for (int off = 1; off < NG; off <<= 1) {
    int u = (tx >= off) ? a[tx - off] : 0;
    __syncthreads();
    a[tx] += u;
    __syncthreads();
  }
  gstart[tx] = a[tx] - v;
  if (tx == NG - 1) gstart[NG] = a[tx];
}

// ---------------- pool = csum / ccnt ----------------
__global__ void pool_kernel(const float* __restrict__ csum, const int* __restrict__ ccnt,
                            float* __restrict__ pool) {
  int g = blockIdx.x, c = threadIdx.x;
  int cnt = ccnt[g];
  pool[(size_t)g * D + c] = cnt > 0 ? csum[(size_t)g * D + c] / (float)cnt : 0.0f;
}

// ---------------- per-graph stable rank of primary nodes -> output row ----------------
__global__ __launch_bounds__(256) void rank_kernel(const int* __restrict__ primary,
                                                   const int* __restrict__ gstart,
                                                   int* __restrict__ pos) {
  int g = blockIdx.x;
  int s = gstart[g], e = gstart[g + 1];
  __shared__ int wcnt[4];
  int run = 0;
  for (int i0 = s; i0 < e; i0 += 256) {
    int n = i0 + threadIdx.x;
    bool valid = n < e;
    int isP = (valid && primary[n] == 1) ? 1 : 0;
    unsigned long long m = __ballot(isP);
    int lane = threadIdx.x & 63;
    int wid = threadIdx.x >> 6;
    if (lane == 0) wcnt[wid] = __popcll(m);
    __syncthreads();
    int pre = __popcll(m & ((1ULL << lane) - 1ULL));
    int woff = 0;
#pragma unroll
    for (int w = 0; w < 4; ++w)
      if (w < wid) woff += wcnt[w];
    int tot = wcnt[0] + wcnt[1] + wcnt[2] + wcnt[3];
    if (valid) pos[n] = isP ? (s + run + woff + pre) : -1;
    run += tot;
    __syncthreads();
  }
}

// ---------------- write out[pos] = [h | pool[g]] ----------------
__global__ __launch_bounds__(256) void write_kernel(
    const float* __restrict__ h, const float* __restrict__ pool,
    const int* __restrict__ batch, const int* __restrict__ pos,
    float* __restrict__ out, int N) {
  long long tid = (long long)blockIdx.x * blockDim.x + threadIdx.x;
  int n = (int)(tid >> 6);
  int c = (int)(tid & 63);
  if (n >= N) return;
  int p = pos[n];
  if (p < 0) return;
  float4 v;
  if (c < 32)
    v = ((const float4*)h)[(size_t)n * 32 + c];
  else
    v = ((const float4*)pool)[(size_t)batch[n] * 32 + (c - 32)];
  ((float4*)out)[(size_t)p * 64 + c] = v;
}

extern "C" void kernel_launch(void* const* d_in, const int* in_sizes, int n_in,
                              void* d_out, int out_size, void* d_ws, size_t ws_size,
                              hipStream_t stream) {
  const float* x = (const float*)d_in[0];
  const int* ei = (const int*)d_in[1];
  const float* ea = (const float*)d_in[2];
  const int* batch = (const int*)d_in[3];
  const int* primary = (const int*)d_in[4];
  const float* W1 = (const float*)d_in[5];
  const float* b1 = (const float*)d_in[6];
  const float* W2 = (const float*)d_in[7];
  const float* b2 = (const float*)d_in[8];
  float* out = (float*)d_out;

  const int N = in_sizes[0] / D;  // 100000
  const int E = in_sizes[1] / 2;  // 1600000
  const int nb = (N + 1023) / 1024;

  // workspace layout (floats unless noted)
  float* y = (float*)d_ws;                           // N*D  (y, then h in-place)
  float* csum = y + (size_t)N * D;                   // NG*D
  float* pool = csum + (size_t)NG * D;               // NG*D
  int2* csr = (int2*)(pool + (size_t)NG * D);        // E int2 (8B aligned: even float offset)
  int* ip = (int*)(csr + (size_t)E);                 // int section:
  int* deg = ip;                                     // N
  int* off = deg + N;                                // N+1 (pad to N+4)
  int* cursor = off + N + 4;                         // N
  int* bsum = cursor + N;                            // nb (pad 128)
  int* ccnt = bsum + 128;                            // NG
  int* ncount = ccnt + NG;                           // NG
  int* gstart = ncount + NG;                         // NG+1 (pad 260)
  int* pos = gstart + 260;                           // N

  // zero: csum (+deg, cursor, ccnt, ncount)
  hipMemsetAsync(csum, 0, (size_t)NG * D * 4, stream);
  hipMemsetAsync(deg, 0, (size_t)N * 4, stream);
  hipMemsetAsync(cursor, 0, (size_t)N * 4, stream);
  hipMemsetAsync(ccnt, 0, (size_t)NG * 2 * 4, stream);  // ccnt + ncount contiguous
  hipMemsetAsync(d_out, 0, (size_t)out_size * 4, stream);

  deg_kernel<<<(E + 255) / 256, 256, 0, stream>>>(ei, deg, E);
  scan_block_sums<<<nb, 256, 0, stream>>>(deg, bsum, N);
  scan_bsum<<<1, 64, 0, stream>>>(bsum, nb);
  scan_final<<<nb, 256, 0, stream>>>(deg, bsum, off, N);
  fill_kernel<<<(E + 255) / 256, 256, 0, stream>>>(ei, off, cursor, csr, E);
  {
    long long threads = (long long)N * 32;
    gather_kernel<<<(int)((threads + 255) / 256), 256, 0, stream>>>(x, ea, csr, off, y, N);
  }
  counts_kernel<<<(N + 255) / 256, 256, 0, stream>>>(batch, primary, ncount, ccnt, N);
  mlp_kernel<<<(N + 7) / 8, 256, 0, stream>>>(y, W1, b1, W2, b2, batch, primary, csum, N);
  scan_kernel<<<1, NG, 0, stream>>>(ncount, gstart);
  pool_kernel<<<NG, D, 0, stream>>>(csum, ccnt, pool);
  rank_kernel<<<NG, 256, 0, stream>>>(primary, gstart, pos);
  write_kernel<<<(int)(((long long)N * 64 + 255) / 256), 256, 0, stream>>>(y, pool, batch, pos, out, N);
}

// Round 3
// 1029.799 us; speedup vs baseline: 3.2632x; 1.0133x over previous
//
#include <hip/hip_runtime.h>

#define D 128
#define NG 256

// ---------------- CSR build: degree histogram ----------------
__global__ __launch_bounds__(256) void deg_kernel(const int* __restrict__ ei,
                                                  int* __restrict__ deg, int E) {
  int e = blockIdx.x * blockDim.x + threadIdx.x;
  if (e < E) atomicAdd(&deg[ei[E + e]], 1);
}

// ---------------- scan over N (3-phase) ----------------
__global__ __launch_bounds__(256) void scan_block_sums(const int* __restrict__ deg,
                                                       int* __restrict__ bsum, int N) {
  __shared__ int red[256];
  int t = threadIdx.x;
  int base = blockIdx.x * 1024;
  int s = 0;
#pragma unroll
  for (int j = 0; j < 4; ++j) {
    int i = base + t * 4 + j;
    if (i < N) s += deg[i];
  }
  red[t] = s;
  __syncthreads();
  for (int o = 128; o > 0; o >>= 1) {
    if (t < o) red[t] += red[t + o];
    __syncthreads();
  }
  if (t == 0) bsum[blockIdx.x] = red[0];
}

__global__ void scan_bsum(int* __restrict__ bsum, int nb) {
  if (threadIdx.x == 0) {
    int run = 0;
    for (int i = 0; i < nb; ++i) {
      int v = bsum[i];
      bsum[i] = run;
      run += v;
    }
  }
}

__global__ __launch_bounds__(256) void scan_final(const int* __restrict__ deg,
                                                  const int* __restrict__ bsum,
                                                  int* __restrict__ off, int N) {
  __shared__ int ts[256];
  int t = threadIdx.x;
  int base = blockIdx.x * 1024;
  int v[4];
  int s = 0;
#pragma unroll
  for (int j = 0; j < 4; ++j) {
    int i = base + t * 4 + j;
    v[j] = (i < N) ? deg[i] : 0;
    s += v[j];
  }
  ts[t] = s;
  __syncthreads();
  for (int o = 1; o < 256; o <<= 1) {
    int u = (t >= o) ? ts[t - o] : 0;
    __syncthreads();
    ts[t] += u;
    __syncthreads();
  }
  int excl = ts[t] - s + bsum[blockIdx.x];
#pragma unroll
  for (int j = 0; j < 4; ++j) {
    int i = base + t * 4 + j;
    if (i < N) off[i] = excl;
    excl += v[j];
    if (i == N - 1) off[N] = excl;
  }
}

// ---------------- CSR fill: csr[off[dst]+slot] = (src, e) ----------------
__global__ __launch_bounds__(256) void fill_kernel(const int* __restrict__ ei,
                                                   const int* __restrict__ off,
                                                   int* __restrict__ cursor,
                                                   int2* __restrict__ csr, int E) {
  int e = blockIdx.x * blockDim.x + threadIdx.x;
  if (e >= E) return;
  int d = ei[E + e];
  int slot = atomicAdd(&cursor[d], 1);
  csr[off[d] + slot] = make_int2(ei[e], e);
}

// ---------------- x -> bf16 (RNE) ----------------
__global__ __launch_bounds__(256) void cvt_kernel(const float* __restrict__ x,
                                                  ushort* __restrict__ xb, int total4) {
  int i = blockIdx.x * blockDim.x + threadIdx.x;
  if (i >= total4) return;
  float4 v = ((const float4*)x)[i];
  uint b[4] = {__float_as_uint(v.x), __float_as_uint(v.y),
               __float_as_uint(v.z), __float_as_uint(v.w)};
  ushort4 o;
  uint r0 = (b[0] + 0x7fffu + ((b[0] >> 16) & 1u)) >> 16;
  uint r1 = (b[1] + 0x7fffu + ((b[1] >> 16) & 1u)) >> 16;
  uint r2 = (b[2] + 0x7fffu + ((b[2] >> 16) & 1u)) >> 16;
  uint r3 = (b[3] + 0x7fffu + ((b[3] >> 16) & 1u)) >> 16;
  o.x = (ushort)r0; o.y = (ushort)r1; o.z = (ushort)r2; o.w = (ushort)r3;
  ((ushort4*)xb)[i] = o;
}

// ---------------- Gather: y[n] = x[n] + sum_{e:(s->n)} (x_bf[s] + ea[e]) ----------------
// 32 threads per node; lane c owns cols 4c..4c+3. x gathered in bf16 (8B/lane).
__global__ __launch_bounds__(256) void gather_kernel(const float* __restrict__ x,
                                                     const ushort* __restrict__ xb,
                                                     const float* __restrict__ ea,
                                                     const int2* __restrict__ csr,
                                                     const int* __restrict__ off,
                                                     float* __restrict__ y, int N) {
  long long tid = (long long)blockIdx.x * blockDim.x + threadIdx.x;
  int n = (int)(tid >> 5);
  int c = (int)(tid & 31);
  if (n >= N) return;
  const float4* ea4 = (const float4*)ea;
  const ushort4* xb4 = (const ushort4*)xb;
  float4 acc = ((const float4*)x)[(size_t)n * 32 + c];
  int s = off[n], e = off[n + 1];
  int k = s;
  for (; k + 2 <= e; k += 2) {
    int2 p0 = csr[k];
    int2 p1 = csr[k + 1];
    float4 a0 = ea4[(size_t)p0.y * 32 + c];
    float4 a1 = ea4[(size_t)p1.y * 32 + c];
    ushort4 u0 = xb4[(size_t)p0.x * 32 + c];
    ushort4 u1 = xb4[(size_t)p1.x * 32 + c];
    acc.x += a0.x + __uint_as_float((uint)u0.x << 16);
    acc.y += a0.y + __uint_as_float((uint)u0.y << 16);
    acc.z += a0.z + __uint_as_float((uint)u0.z << 16);
    acc.w += a0.w + __uint_as_float((uint)u0.w << 16);
    acc.x += a1.x + __uint_as_float((uint)u1.x << 16);
    acc.y += a1.y + __uint_as_float((uint)u1.y << 16);
    acc.z += a1.z + __uint_as_float((uint)u1.z << 16);
    acc.w += a1.w + __uint_as_float((uint)u1.w << 16);
  }
  if (k < e) {
    int2 p0 = csr[k];
    float4 a0 = ea4[(size_t)p0.y * 32 + c];
    ushort4 u0 = xb4[(size_t)p0.x * 32 + c];
    acc.x += a0.x + __uint_as_float((uint)u0.x << 16);
    acc.y += a0.y + __uint_as_float((uint)u0.y << 16);
    acc.z += a0.z + __uint_as_float((uint)u0.z << 16);
    acc.w += a0.w + __uint_as_float((uint)u0.w << 16);
  }
  ((float4*)y)[(size_t)n * 32 + c] = acc;
}

// ---------------- per-graph node/cond counts ----------------
__global__ void counts_kernel(const int* __restrict__ batch, const int* __restrict__ primary,
                              int* __restrict__ ncount, int* __restrict__ ccnt, int N) {
  int n = blockIdx.x * blockDim.x + threadIdx.x;
  if (n >= N) return;
  int g = batch[n];
  atomicAdd(&ncount[g], 1);
  if (primary[n] == 0) atomicAdd(&ccnt[g], 1);
}

// ---------------- MLP h = relu(y@W1+b1)@W2+b2, in-place over y; fused cond-pool sum ----------------
__global__ __launch_bounds__(256) void mlp_kernel(
    float* __restrict__ y,
    const float* __restrict__ W1, const float* __restrict__ b1,
    const float* __restrict__ W2, const float* __restrict__ b2,
    const int* __restrict__ batch, const int* __restrict__ primary,
    float* __restrict__ csum, int N) {
  __shared__ float ys[8][D];
  __shared__ float ts[8][D];
  int tid = threadIdx.x;
  int r = tid >> 5;
  int c4 = tid & 31;
  int base = blockIdx.x * 8;
  int n = base + r;

  {
    float4 v = make_float4(0.f, 0.f, 0.f, 0.f);
    if (n < N) v = ((const float4*)y)[(size_t)n * 32 + c4];
    ((float4*)&ys[r][0])[c4] = v;
  }
  __syncthreads();

  const float4* W1_4 = (const float4*)W1;
  float4 acc = ((const float4*)b1)[c4];
#pragma unroll 8
  for (int k = 0; k < D; ++k) {
    float yv = ys[r][k];
    float4 w = W1_4[k * 32 + c4];
    acc.x += yv * w.x; acc.y += yv * w.y; acc.z += yv * w.z; acc.w += yv * w.w;
  }
  acc.x = acc.x > 0.f ? acc.x : 0.f;
  acc.y = acc.y > 0.f ? acc.y : 0.f;
  acc.z = acc.z > 0.f ? acc.z : 0.f;
  acc.w = acc.w > 0.f ? acc.w : 0.f;
  ((float4*)&ts[r][0])[c4] = acc;
  __syncthreads();

  const float4* W2_4 = (const float4*)W2;
  float4 acc2 = ((const float4*)b2)[c4];
#pragma unroll 8
  for (int k = 0; k < D; ++k) {
    float tv = ts[r][k];
    float4 w = W2_4[k * 32 + c4];
    acc2.x += tv * w.x; acc2.y += tv * w.y; acc2.z += tv * w.z; acc2.w += tv * w.w;
  }

  if (n < N) {
    ((float4*)y)[(size_t)n * 32 + c4] = acc2;  // h overwrites y (row-local, safe)
    if (primary[n] == 0) {
      int g = batch[n];
      float* cs = csum + (size_t)g * D + (size_t)c4 * 4;
      unsafeAtomicAdd(cs + 0, acc2.x);
      unsafeAtomicAdd(cs + 1, acc2.y);
      unsafeAtomicAdd(cs + 2, acc2.z);
      unsafeAtomicAdd(cs + 3, acc2.w);
    }
  }
}

// ---------------- exclusive scan of graph sizes -> gstart ----------------
__global__ void scan_kernel(const int* __restrict__ ncount, int* __restrict__ gstart) {
  __shared__ int a[NG];
  int tx = threadIdx.x;
  int v = ncount[tx];
  a[tx] = v;
  __syncthreads();
  for (int off = 1; off < NG; off <<= 1) {
    int u = (tx >= off) ? a[tx - off] : 0;
    __syncthreads();
    a[tx] += u;
    __syncthreads();
  }
  gstart[tx] = a[tx] - v;
  if (tx == NG - 1) gstart[NG] = a[tx];
}

// ---------------- pool = csum / ccnt ----------------
__global__ void pool_kernel(const float* __restrict__ csum, const int* __restrict__ ccnt,
                            float* __restrict__ pool) {
  int g = blockIdx.x, c = threadIdx.x;
  int cnt = ccnt[g];
  pool[(size_t)g * D + c] = cnt > 0 ? csum[(size_t)g * D + c] / (float)cnt : 0.0f;
}

// ---------------- per-graph stable rank of primary nodes -> output row ----------------
__global__ __launch_bounds__(256) void rank_kernel(const int* __restrict__ primary,
                                                   const int* __restrict__ gstart,
                                                   int* __restrict__ pos) {
  int g = blockIdx.x;
  int s = gstart[g], e = gstart[g + 1];
  __shared__ int wcnt[4];
  int run = 0;
  for (int i0 = s; i0 < e; i0 += 256) {
    int n = i0 + threadIdx.x;
    bool valid = n < e;
    int isP = (valid && primary[n] == 1) ? 1 : 0;
    unsigned long long m = __ballot(isP);
    int lane = threadIdx.x & 63;
    int wid = threadIdx.x >> 6;
    if (lane == 0) wcnt[wid] = __popcll(m);
    __syncthreads();
    int pre = __popcll(m & ((1ULL << lane) - 1ULL));
    int woff = 0;
#pragma unroll
    for (int w = 0; w < 4; ++w)
      if (w < wid) woff += wcnt[w];
    int tot = wcnt[0] + wcnt[1] + wcnt[2] + wcnt[3];
    if (valid) pos[n] = isP ? (s + run + woff + pre) : -1;
    run += tot;
    __syncthreads();
  }
}

// ---------------- write out[pos] = [h | pool[g]] ----------------
__global__ __launch_bounds__(256) void write_kernel(
    const float* __restrict__ h, const float* __restrict__ pool,
    const int* __restrict__ batch, const int* __restrict__ pos,
    float* __restrict__ out, int N) {
  long long tid = (long long)blockIdx.x * blockDim.x + threadIdx.x;
  int n = (int)(tid >> 6);
  int c = (int)(tid & 63);
  if (n >= N) return;
  int p = pos[n];
  if (p < 0) return;
  float4 v;
  if (c < 32)
    v = ((const float4*)h)[(size_t)n * 32 + c];
  else
    v = ((const float4*)pool)[(size_t)batch[n] * 32 + (c - 32)];
  ((float4*)out)[(size_t)p * 64 + c] = v;
}

extern "C" void kernel_launch(void* const* d_in, const int* in_sizes, int n_in,
                              void* d_out, int out_size, void* d_ws, size_t ws_size,
                              hipStream_t stream) {
  const float* x = (const float*)d_in[0];
  const int* ei = (const int*)d_in[1];
  const float* ea = (const float*)d_in[2];
  const int* batch = (const int*)d_in[3];
  const int* primary = (const int*)d_in[4];
  const float* W1 = (const float*)d_in[5];
  const float* b1 = (const float*)d_in[6];
  const float* W2 = (const float*)d_in[7];
  const float* b2 = (const float*)d_in[8];
  float* out = (float*)d_out;

  const int N = in_sizes[0] / D;  // 100000
  const int E = in_sizes[1] / 2;  // 1600000
  const int nb = (N + 1023) / 1024;

  // workspace layout
  float* y = (float*)d_ws;                           // N*D  (y, then h in-place)
  float* csum = y + (size_t)N * D;                   // NG*D
  float* pool = csum + (size_t)NG * D;               // NG*D
  int2* csr = (int2*)(pool + (size_t)NG * D);        // E int2
  ushort* xb = (ushort*)(csr + (size_t)E);           // N*D bf16 (even count -> int-aligned after)
  int* ip = (int*)(xb + (size_t)N * D);              // int section:
  int* deg = ip;                                     // N
  int* off = deg + N;                                // N+1 (pad to N+4)
  int* cursor = off + N + 4;                         // N
  int* bsum = cursor + N;                            // nb (pad 128)
  int* ccnt = bsum + 128;                            // NG
  int* ncount = ccnt + NG;                           // NG
  int* gstart = ncount + NG;                         // NG+1 (pad 260)
  int* pos = gstart + 260;                           // N

  hipMemsetAsync(csum, 0, (size_t)NG * D * 4, stream);
  hipMemsetAsync(deg, 0, (size_t)N * 4, stream);
  hipMemsetAsync(cursor, 0, (size_t)N * 4, stream);
  hipMemsetAsync(ccnt, 0, (size_t)NG * 2 * 4, stream);  // ccnt + ncount contiguous
  hipMemsetAsync(d_out, 0, (size_t)out_size * 4, stream);

  deg_kernel<<<(E + 255) / 256, 256, 0, stream>>>(ei, deg, E);
  scan_block_sums<<<nb, 256, 0, stream>>>(deg, bsum, N);
  scan_bsum<<<1, 64, 0, stream>>>(bsum, nb);
  scan_final<<<nb, 256, 0, stream>>>(deg, bsum, off, N);
  fill_kernel<<<(E + 255) / 256, 256, 0, stream>>>(ei, off, cursor, csr, E);
  cvt_kernel<<<((N * D / 4) + 255) / 256, 256, 0, stream>>>(x, xb, N * D / 4);
  {
    long long threads = (long long)N * 32;
    gather_kernel<<<(int)((threads + 255) / 256), 256, 0, stream>>>(x, xb, ea, csr, off, y, N);
  }
  counts_kernel<<<(N + 255) / 256, 256, 0, stream>>>(batch, primary, ncount, ccnt, N);
  mlp_kernel<<<(N + 7) / 8, 256, 0, stream>>>(y, W1, b1, W2, b2, batch, primary, csum, N);
  scan_kernel<<<1, NG, 0, stream>>>(ncount, gstart);
  pool_kernel<<<NG, D, 0, stream>>>(csum, ccnt, pool);
  rank_kernel<<<NG, 256, 0, stream>>>(primary, gstart, pos);
  write_kernel<<<(int)(((long long)N * 64 + 255) / 256), 256, 0, stream>>>(y, pool, batch, pos, out, N);
}

// Round 4
// 664.235 us; speedup vs baseline: 5.0592x; 1.5504x over previous
//
#include <hip/hip_runtime.h>

#define D 128
#define NG 256

typedef __attribute__((ext_vector_type(8))) short bf16x8;
typedef __attribute__((ext_vector_type(4))) float f32x4;

__device__ inline ushort f2bf(float f) {
  uint b = __float_as_uint(f);
  return (ushort)((b + 0x7fffu + ((b >> 16) & 1u)) >> 16);
}

// ---------------- CSR build: degree histogram ----------------
__global__ __launch_bounds__(256) void deg_kernel(const int* __restrict__ ei,
                                                  int* __restrict__ deg, int E) {
  int e = blockIdx.x * blockDim.x + threadIdx.x;
  if (e < E) atomicAdd(&deg[ei[E + e]], 1);
}

// ---------------- scan over N (3-phase) ----------------
__global__ __launch_bounds__(256) void scan_block_sums(const int* __restrict__ deg,
                                                       int* __restrict__ bsum, int N) {
  __shared__ int red[256];
  int t = threadIdx.x;
  int base = blockIdx.x * 1024;
  int s = 0;
#pragma unroll
  for (int j = 0; j < 4; ++j) {
    int i = base + t * 4 + j;
    if (i < N) s += deg[i];
  }
  red[t] = s;
  __syncthreads();
  for (int o = 128; o > 0; o >>= 1) {
    if (t < o) red[t] += red[t + o];
    __syncthreads();
  }
  if (t == 0) bsum[blockIdx.x] = red[0];
}

__global__ void scan_bsum(int* __restrict__ bsum, int nb) {
  if (threadIdx.x == 0) {
    int run = 0;
    for (int i = 0; i < nb; ++i) {
      int v = bsum[i];
      bsum[i] = run;
      run += v;
    }
  }
}

__global__ __launch_bounds__(256) void scan_final(const int* __restrict__ deg,
                                                  const int* __restrict__ bsum,
                                                  int* __restrict__ off, int N) {
  __shared__ int ts[256];
  int t = threadIdx.x;
  int base = blockIdx.x * 1024;
  int v[4];
  int s = 0;
#pragma unroll
  for (int j = 0; j < 4; ++j) {
    int i = base + t * 4 + j;
    v[j] = (i < N) ? deg[i] : 0;
    s += v[j];
  }
  ts[t] = s;
  __syncthreads();
  for (int o = 1; o < 256; o <<= 1) {
    int u = (t >= o) ? ts[t - o] : 0;
    __syncthreads();
    ts[t] += u;
    __syncthreads();
  }
  int excl = ts[t] - s + bsum[blockIdx.x];
#pragma unroll
  for (int j = 0; j < 4; ++j) {
    int i = base + t * 4 + j;
    if (i < N) off[i] = excl;
    excl += v[j];
    if (i == N - 1) off[N] = excl;
  }
}

// ---------------- CSR fill: csr[off[dst]+slot] = (src, e) ----------------
__global__ __launch_bounds__(256) void fill_kernel(const int* __restrict__ ei,
                                                   const int* __restrict__ off,
                                                   int* __restrict__ cursor,
                                                   int2* __restrict__ csr, int E) {
  int e = blockIdx.x * blockDim.x + threadIdx.x;
  if (e >= E) return;
  int d = ei[E + e];
  int slot = atomicAdd(&cursor[d], 1);
  csr[off[d] + slot] = make_int2(ei[e], e);
}

// ---------------- x -> bf16 (RNE) ----------------
__global__ __launch_bounds__(256) void cvt_kernel(const float* __restrict__ x,
                                                  ushort* __restrict__ xb, int total4) {
  int i = blockIdx.x * blockDim.x + threadIdx.x;
  if (i >= total4) return;
  float4 v = ((const float4*)x)[i];
  ushort4 o;
  o.x = f2bf(v.x); o.y = f2bf(v.y); o.z = f2bf(v.z); o.w = f2bf(v.w);
  ((ushort4*)xb)[i] = o;
}

// ---------------- W -> transposed bf16: WT[n][k] = bf16(W[k][n]) ----------------
__global__ __launch_bounds__(256) void cvtW_kernel(const float* __restrict__ W1,
                                                   const float* __restrict__ W2,
                                                   ushort* __restrict__ W1T,
                                                   ushort* __restrict__ W2T) {
  int idx = blockIdx.x * blockDim.x + threadIdx.x;  // 2*128*128 total
  int w = idx >> 14;
  int k = (idx >> 7) & 127;
  int n = idx & 127;
  const float* src = w ? W2 : W1;
  ushort* dst = w ? W2T : W1T;
  dst[n * 128 + k] = f2bf(src[k * 128 + n]);
}

// ---------------- Gather: yb[n] = bf16( x[n] + sum_{e:(s->n)} (x_bf[s] + ea[e]) ) -------
__global__ __launch_bounds__(256) void gather_kernel(const ushort* __restrict__ xb,
                                                     const float* __restrict__ ea,
                                                     const int2* __restrict__ csr,
                                                     const int* __restrict__ off,
                                                     ushort* __restrict__ yb, int N) {
  long long tid = (long long)blockIdx.x * blockDim.x + threadIdx.x;
  int n = (int)(tid >> 5);
  int c = (int)(tid & 31);
  if (n >= N) return;
  const float4* ea4 = (const float4*)ea;
  const ushort4* xb4 = (const ushort4*)xb;
  ushort4 self = xb4[(size_t)n * 32 + c];
  float4 acc = make_float4(__uint_as_float((uint)self.x << 16),
                           __uint_as_float((uint)self.y << 16),
                           __uint_as_float((uint)self.z << 16),
                           __uint_as_float((uint)self.w << 16));
  int s = off[n], e = off[n + 1];
  int k = s;
  for (; k + 2 <= e; k += 2) {
    int2 p0 = csr[k];
    int2 p1 = csr[k + 1];
    float4 a0 = ea4[(size_t)p0.y * 32 + c];
    float4 a1 = ea4[(size_t)p1.y * 32 + c];
    ushort4 u0 = xb4[(size_t)p0.x * 32 + c];
    ushort4 u1 = xb4[(size_t)p1.x * 32 + c];
    acc.x += a0.x + __uint_as_float((uint)u0.x << 16);
    acc.y += a0.y + __uint_as_float((uint)u0.y << 16);
    acc.z += a0.z + __uint_as_float((uint)u0.z << 16);
    acc.w += a0.w + __uint_as_float((uint)u0.w << 16);
    acc.x += a1.x + __uint_as_float((uint)u1.x << 16);
    acc.y += a1.y + __uint_as_float((uint)u1.y << 16);
    acc.z += a1.z + __uint_as_float((uint)u1.z << 16);
    acc.w += a1.w + __uint_as_float((uint)u1.w << 16);
  }
  if (k < e) {
    int2 p0 = csr[k];
    float4 a0 = ea4[(size_t)p0.y * 32 + c];
    ushort4 u0 = xb4[(size_t)p0.x * 32 + c];
    acc.x += a0.x + __uint_as_float((uint)u0.x << 16);
    acc.y += a0.y + __uint_as_float((uint)u0.y << 16);
    acc.z += a0.z + __uint_as_float((uint)u0.z << 16);
    acc.w += a0.w + __uint_as_float((uint)u0.w << 16);
  }
  ushort4 o;
  o.x = f2bf(acc.x); o.y = f2bf(acc.y); o.z = f2bf(acc.z); o.w = f2bf(acc.w);
  ((ushort4*)yb)[(size_t)n * 32 + c] = o;
}

// ---------------- per-graph node/cond counts ----------------
__global__ void counts_kernel(const int* __restrict__ batch, const int* __restrict__ primary,
                              int* __restrict__ ncount, int* __restrict__ ccnt, int N) {
  int n = blockIdx.x * blockDim.x + threadIdx.x;
  if (n >= N) return;
  int g = batch[n];
  atomicAdd(&ncount[g], 1);
  if (primary[n] == 0) atomicAdd(&ccnt[g], 1);
}

// ---------------- MFMA MLP: h = relu(yb@W1+b1)@W2+b2 ; fused cond-pool (LDS-reduced) ----
// 256 threads = 4 waves; wave w computes 16 rows; block = 64 rows.
__global__ __launch_bounds__(256) void mlp_mfma_kernel(
    const ushort* __restrict__ yb, float* __restrict__ h,
    const ushort* __restrict__ W1T, const float* __restrict__ b1,
    const ushort* __restrict__ W2T, const float* __restrict__ b2,
    const int* __restrict__ batch, const int* __restrict__ primary,
    float* __restrict__ csum, int N) {
  __shared__ ushort tl[4][16][D];  // per-wave relu(t) tile, XOR-swizzled cols
  __shared__ float csl[4][D];      // local csum for up to 4 graphs
  const int tid = threadIdx.x;
  const int w = tid >> 6;
  const int l = tid & 63;
  const int lr = l & 15;
  const int lg = l >> 4;
  const int base = blockIdx.x * 64;
  const int m0 = base + w * 16;

  for (int i = tid; i < 4 * D; i += 256) ((float*)csl)[i] = 0.f;
  int gmin = batch[base < N ? base : N - 1];
  __syncthreads();

  // ---- GEMM1: t = relu(y @ W1 + b1) ----
  f32x4 acc[8];
#pragma unroll
  for (int t = 0; t < 8; ++t) {
    float bv = b1[t * 16 + lr];
    acc[t][0] = bv; acc[t][1] = bv; acc[t][2] = bv; acc[t][3] = bv;
  }
  int arow = m0 + lr;
  if (arow >= N) arow = N - 1;
#pragma unroll
  for (int kk = 0; kk < 4; ++kk) {
    bf16x8 a = *(const bf16x8*)&yb[(size_t)arow * D + kk * 32 + lg * 8];
#pragma unroll
    for (int t = 0; t < 8; ++t) {
      bf16x8 b = *(const bf16x8*)&W1T[(size_t)(t * 16 + lr) * D + kk * 32 + lg * 8];
      acc[t] = __builtin_amdgcn_mfma_f32_16x16x32_bf16(a, b, acc[t], 0, 0, 0);
    }
  }
  // relu + cvt + store to per-wave LDS tile ([m][n], col ^= (m&7)<<3)
#pragma unroll
  for (int t = 0; t < 8; ++t) {
#pragma unroll
    for (int r = 0; r < 4; ++r) {
      float v = acc[t][r];
      v = v > 0.f ? v : 0.f;
      int m = lg * 4 + r;
      int col = (t * 16 + lr) ^ ((m & 7) << 3);
      tl[w][m][col] = f2bf(v);
    }
  }
  __syncthreads();

  // ---- GEMM2: h = t @ W2 + b2 ----
  f32x4 acc2[8];
#pragma unroll
  for (int t = 0; t < 8; ++t) {
    float bv = b2[t * 16 + lr];
    acc2[t][0] = bv; acc2[t][1] = bv; acc2[t][2] = bv; acc2[t][3] = bv;
  }
#pragma unroll
  for (int kk = 0; kk < 4; ++kk) {
    bf16x8 a = *(const bf16x8*)&tl[w][lr][(kk * 32 + lg * 8) ^ ((lr & 7) << 3)];
#pragma unroll
    for (int t = 0; t < 8; ++t) {
      bf16x8 b = *(const bf16x8*)&W2T[(size_t)(t * 16 + lr) * D + kk * 32 + lg * 8];
      acc2[t] = __builtin_amdgcn_mfma_f32_16x16x32_bf16(a, b, acc2[t], 0, 0, 0);
    }
  }

  // ---- epilogue: store h rows + cond-pool accumulation ----
#pragma unroll
  for (int r = 0; r < 4; ++r) {
    int m = m0 + lg * 4 + r;
    if (m >= N) continue;
    bool cond = (primary[m] == 0);
    int g = batch[m];
    int gl = g - gmin;
#pragma unroll
    for (int t = 0; t < 8; ++t) {
      float v = acc2[t][r];
      h[(size_t)m * D + t * 16 + lr] = v;
      if (cond) {
        if (gl < 4) atomicAdd(&csl[gl][t * 16 + lr], v);
        else unsafeAtomicAdd(&csum[(size_t)g * D + t * 16 + lr], v);
      }
    }
  }
  __syncthreads();
  for (int i = tid; i < 4 * D; i += 256) {
    float v = ((float*)csl)[i];
    if (v != 0.f) {
      int gl = i >> 7, c = i & 127;
      unsafeAtomicAdd(&csum[(size_t)(gmin + gl) * D + c], v);
    }
  }
}

// ---------------- exclusive scan of graph sizes -> gstart ----------------
__global__ void scan_kernel(const int* __restrict__ ncount, int* __restrict__ gstart) {
  __shared__ int a[NG];
  int tx = threadIdx.x;
  int v = ncount[tx];
  a[tx] = v;
  __syncthreads();
  for (int off = 1; off < NG; off <<= 1) {
    int u = (tx >= off) ? a[tx - off] : 0;
    __syncthreads();
    a[tx] += u;
    __syncthreads();
  }
  gstart[tx] = a[tx] - v;
  if (tx == NG - 1) gstart[NG] = a[tx];
}

// ---------------- pool = csum / ccnt ----------------
__global__ void pool_kernel(const float* __restrict__ csum, const int* __restrict__ ccnt,
                            float* __restrict__ pool) {
  int g = blockIdx.x, c = threadIdx.x;
  int cnt = ccnt[g];
  pool[(size_t)g * D + c] = cnt > 0 ? csum[(size_t)g * D + c] / (float)cnt : 0.0f;
}

// ---------------- per-graph stable ranks: primary -> p, cond -> ~p ----------------
__global__ __launch_bounds__(256) void rank_kernel(const int* __restrict__ primary,
                                                   const int* __restrict__ gstart,
                                                   const int* __restrict__ ccnt,
                                                   int* __restrict__ pos) {
  int g = blockIdx.x;
  int s = gstart[g], e = gstart[g + 1];
  int pcnt = (e - s) - ccnt[g];
  __shared__ int wcntP[4], wcntC[4];
  int prun = 0, crun = 0;
  for (int i0 = s; i0 < e; i0 += 256) {
    int n = i0 + threadIdx.x;
    bool valid = n < e;
    int isP = (valid && primary[n] == 1) ? 1 : 0;
    int isC = (valid && primary[n] != 1) ? 1 : 0;
    unsigned long long mP = __ballot(isP);
    unsigned long long mC = __ballot(isC);
    int lane = threadIdx.x & 63;
    int wid = threadIdx.x >> 6;
    if (lane == 0) { wcntP[wid] = __popcll(mP); wcntC[wid] = __popcll(mC); }
    __syncthreads();
    int preP = __popcll(mP & ((1ULL << lane) - 1ULL));
    int preC = __popcll(mC & ((1ULL << lane) - 1ULL));
    int woffP = 0, woffC = 0;
#pragma unroll
    for (int ww = 0; ww < 4; ++ww)
      if (ww < wid) { woffP += wcntP[ww]; woffC += wcntC[ww]; }
    int totP = wcntP[0] + wcntP[1] + wcntP[2] + wcntP[3];
    int totC = wcntC[0] + wcntC[1] + wcntC[2] + wcntC[3];
    if (valid) {
      if (isP)
        pos[n] = s + prun + woffP + preP;
      else
        pos[n] = ~(s + pcnt + crun + woffC + preC);
    }
    prun += totP;
    crun += totC;
    __syncthreads();
  }
}

// ---------------- write out: primary -> [h | pool[g]], cond -> zeros ----------------
__global__ __launch_bounds__(256) void write_kernel(
    const float* __restrict__ h, const float* __restrict__ pool,
    const int* __restrict__ batch, const int* __restrict__ pos,
    float* __restrict__ out, int N) {
  long long tid = (long long)blockIdx.x * blockDim.x + threadIdx.x;
  int n = (int)(tid >> 6);
  int c = (int)(tid & 63);
  if (n >= N) return;
  int p = pos[n];
  float4 v = make_float4(0.f, 0.f, 0.f, 0.f);
  int pp;
  if (p >= 0) {
    pp = p;
    if (c < 32)
      v = ((const float4*)h)[(size_t)n * 32 + c];
    else
      v = ((const float4*)pool)[(size_t)batch[n] * 32 + (c - 32)];
  } else {
    pp = ~p;
  }
  ((float4*)out)[(size_t)pp * 64 + c] = v;
}

extern "C" void kernel_launch(void* const* d_in, const int* in_sizes, int n_in,
                              void* d_out, int out_size, void* d_ws, size_t ws_size,
                              hipStream_t stream) {
  const float* x = (const float*)d_in[0];
  const int* ei = (const int*)d_in[1];
  const float* ea = (const float*)d_in[2];
  const int* batch = (const int*)d_in[3];
  const int* primary = (const int*)d_in[4];
  const float* W1 = (const float*)d_in[5];
  const float* b1 = (const float*)d_in[6];
  const float* W2 = (const float*)d_in[7];
  const float* b2 = (const float*)d_in[8];
  float* out = (float*)d_out;

  const int N = in_sizes[0] / D;  // 100000
  const int E = in_sizes[1] / 2;  // 1600000
  const int nb = (N + 1023) / 1024;

  // workspace layout (all segment sizes are multiples of 256B)
  float* h = (float*)d_ws;                           // N*D f32
  float* csum = h + (size_t)N * D;                   // NG*D
  float* pool = csum + (size_t)NG * D;               // NG*D
  ushort* yb = (ushort*)(pool + (size_t)NG * D);     // N*D bf16
  ushort* xb = yb + (size_t)N * D;                   // N*D bf16
  ushort* W1T = xb + (size_t)N * D;                  // 128*128 bf16
  ushort* W2T = W1T + D * D;                         // 128*128 bf16
  int2* csr = (int2*)(W2T + D * D);                  // E int2
  int* ip = (int*)(csr + (size_t)E);
  int* deg = ip;                                     // N
  int* off = deg + N;                                // N+1 (pad 4)
  int* cursor = off + N + 4;                         // N
  int* bsum = cursor + N;                            // nb (pad 128)
  int* ccnt = bsum + 128;                            // NG
  int* ncount = ccnt + NG;                           // NG
  int* gstart = ncount + NG;                         // NG+1 (pad 260)
  int* pos = gstart + 260;                           // N

  hipMemsetAsync(csum, 0, (size_t)NG * D * 4, stream);
  hipMemsetAsync(deg, 0, (size_t)N * 4, stream);
  hipMemsetAsync(cursor, 0, (size_t)N * 4, stream);
  hipMemsetAsync(ccnt, 0, (size_t)NG * 2 * 4, stream);  // ccnt + ncount contiguous

  deg_kernel<<<(E + 255) / 256, 256, 0, stream>>>(ei, deg, E);
  scan_block_sums<<<nb, 256, 0, stream>>>(deg, bsum, N);
  scan_bsum<<<1, 64, 0, stream>>>(bsum, nb);
  scan_final<<<nb, 256, 0, stream>>>(deg, bsum, off, N);
  fill_kernel<<<(E + 255) / 256, 256, 0, stream>>>(ei, off, cursor, csr, E);
  cvt_kernel<<<((N * D / 4) + 255) / 256, 256, 0, stream>>>(x, xb, N * D / 4);
  cvtW_kernel<<<(2 * D * D + 255) / 256, 256, 0, stream>>>(W1, W2, W1T, W2T);
  {
    long long threads = (long long)N * 32;
    gather_kernel<<<(int)((threads + 255) / 256), 256, 0, stream>>>(xb, ea, csr, off, yb, N);
  }
  counts_kernel<<<(N + 255) / 256, 256, 0, stream>>>(batch, primary, ncount, ccnt, N);
  mlp_mfma_kernel<<<(N + 63) / 64, 256, 0, stream>>>(yb, h, W1T, b1, W2T, b2, batch, primary,
                                                     csum, N);
  scan_kernel<<<1, NG, 0, stream>>>(ncount, gstart);
  pool_kernel<<<NG, D, 0, stream>>>(csum, ccnt, pool);
  rank_kernel<<<NG, 256, 0, stream>>>(primary, gstart, ccnt, pos);
  write_kernel<<<(int)(((long long)N * 64 + 255) / 256), 256, 0, stream>>>(h, pool, batch, pos,
                                                                           out, N);
}

// Round 5
// 648.212 us; speedup vs baseline: 5.1842x; 1.0247x over previous
//
#include <hip/hip_runtime.h>

#define D 128
#define NG 256

typedef __attribute__((ext_vector_type(8))) short bf16x8;
typedef __attribute__((ext_vector_type(4))) float f32x4;
typedef __attribute__((ext_vector_type(4))) float f4;
typedef __attribute__((ext_vector_type(2))) int i2;
typedef __attribute__((ext_vector_type(4))) ushort u16x4;

__device__ inline ushort f2bf(float f) {
  uint b = __float_as_uint(f);
  return (ushort)((b + 0x7fffu + ((b >> 16) & 1u)) >> 16);
}
__device__ inline float bf2f(ushort u) { return __uint_as_float((uint)u << 16); }

// ---------------- deg histogram + per-graph counts (fused) ----------------
__global__ __launch_bounds__(256) void deg_counts_kernel(const int* __restrict__ ei,
                                                         int* __restrict__ deg,
                                                         const int* __restrict__ batch,
                                                         const int* __restrict__ primary,
                                                         int* __restrict__ ncount,
                                                         int* __restrict__ ccnt, int E, int N) {
  int e = blockIdx.x * blockDim.x + threadIdx.x;
  if (e < E) {
    int d = __builtin_nontemporal_load(&ei[E + e]);
    atomicAdd(&deg[d], 1);
  }
  if (e < N) {
    int g = batch[e];
    atomicAdd(&ncount[g], 1);
    if (primary[e] == 0) atomicAdd(&ccnt[g], 1);
  }
}

// ---------------- scan over N (3-phase) ----------------
__global__ __launch_bounds__(256) void scan_block_sums(const int* __restrict__ deg,
                                                       int* __restrict__ bsum, int N) {
  __shared__ int red[256];
  int t = threadIdx.x;
  int base = blockIdx.x * 1024;
  int s = 0;
#pragma unroll
  for (int j = 0; j < 4; ++j) {
    int i = base + t * 4 + j;
    if (i < N) s += deg[i];
  }
  red[t] = s;
  __syncthreads();
  for (int o = 128; o > 0; o >>= 1) {
    if (t < o) red[t] += red[t + o];
    __syncthreads();
  }
  if (t == 0) bsum[blockIdx.x] = red[0];
}

__global__ void scan_bsum(int* __restrict__ bsum, int nb) {
  if (threadIdx.x == 0) {
    int run = 0;
    for (int i = 0; i < nb; ++i) {
      int v = bsum[i];
      bsum[i] = run;
      run += v;
    }
  }
}

__global__ __launch_bounds__(256) void scan_final(const int* __restrict__ deg,
                                                  const int* __restrict__ bsum,
                                                  int* __restrict__ off, int N) {
  __shared__ int ts[256];
  int t = threadIdx.x;
  int base = blockIdx.x * 1024;
  int v[4];
  int s = 0;
#pragma unroll
  for (int j = 0; j < 4; ++j) {
    int i = base + t * 4 + j;
    v[j] = (i < N) ? deg[i] : 0;
    s += v[j];
  }
  ts[t] = s;
  __syncthreads();
  for (int o = 1; o < 256; o <<= 1) {
    int u = (t >= o) ? ts[t - o] : 0;
    __syncthreads();
    ts[t] += u;
    __syncthreads();
  }
  int excl = ts[t] - s + bsum[blockIdx.x];
#pragma unroll
  for (int j = 0; j < 4; ++j) {
    int i = base + t * 4 + j;
    if (i < N) off[i] = excl;
    excl += v[j];
    if (i == N - 1) off[N] = excl;
  }
}

// ---------------- CSR fill: csr[off[dst]+slot] = (src, e) ----------------
__global__ __launch_bounds__(256) void fill_kernel(const int* __restrict__ ei,
                                                   const int* __restrict__ off,
                                                   int* __restrict__ cursor,
                                                   i2* __restrict__ csr, int E) {
  int e = blockIdx.x * blockDim.x + threadIdx.x;
  if (e >= E) return;
  int s = __builtin_nontemporal_load(&ei[e]);
  int d = __builtin_nontemporal_load(&ei[E + e]);
  int slot = atomicAdd(&cursor[d], 1);
  i2 v;
  v.x = s;
  v.y = e;
  __builtin_nontemporal_store(v, &csr[off[d] + slot]);
}

// ---------------- x -> bf16 (RNE) + W -> transposed bf16 (fused) ----------------
__global__ __launch_bounds__(256) void cvt_kernel(const float* __restrict__ x,
                                                  ushort* __restrict__ xb,
                                                  const float* __restrict__ W1,
                                                  const float* __restrict__ W2,
                                                  ushort* __restrict__ W1T,
                                                  ushort* __restrict__ W2T, int total4) {
  int i = blockIdx.x * blockDim.x + threadIdx.x;
  if (i < total4) {
    f4 v = __builtin_nontemporal_load(&((const f4*)x)[i]);
    u16x4 o;
    o.x = f2bf(v.x);
    o.y = f2bf(v.y);
    o.z = f2bf(v.z);
    o.w = f2bf(v.w);
    ((u16x4*)xb)[i] = o;
  }
  if (i < 2 * D * D) {
    int w = i >> 14;
    int k = (i >> 7) & 127;
    int n = i & 127;
    const float* src = w ? W2 : W1;
    ushort* dst = w ? W2T : W1T;
    dst[n * 128 + k] = f2bf(src[k * 128 + n]);
  }
}

// ---------------- Gather: yb[n] = bf16( x[n] + sum_{e:(s->n)} (x_bf[s] + ea[e]) ) -------
// 32 threads per node; lane c owns cols 4c..4c+3. ea/csr nontemporal, xb cached.
__global__ __launch_bounds__(256) void gather_kernel(const ushort* __restrict__ xb,
                                                     const float* __restrict__ ea,
                                                     const i2* __restrict__ csr,
                                                     const int* __restrict__ off,
                                                     ushort* __restrict__ yb, int N) {
  long long tid = (long long)blockIdx.x * blockDim.x + threadIdx.x;
  int n = (int)(tid >> 5);
  int c = (int)(tid & 31);
  if (n >= N) return;
  const f4* ea4 = (const f4*)ea;
  const u16x4* xb4 = (const u16x4*)xb;
  u16x4 self = xb4[(size_t)n * 32 + c];
  f4 acc;
  acc.x = bf2f(self.x);
  acc.y = bf2f(self.y);
  acc.z = bf2f(self.z);
  acc.w = bf2f(self.w);
  int s = off[n], e = off[n + 1];
  int k = s;
  for (; k + 4 <= e; k += 4) {
    i2 p0 = __builtin_nontemporal_load(&csr[k]);
    i2 p1 = __builtin_nontemporal_load(&csr[k + 1]);
    i2 p2 = __builtin_nontemporal_load(&csr[k + 2]);
    i2 p3 = __builtin_nontemporal_load(&csr[k + 3]);
    f4 a0 = __builtin_nontemporal_load(&ea4[(size_t)p0.y * 32 + c]);
    f4 a1 = __builtin_nontemporal_load(&ea4[(size_t)p1.y * 32 + c]);
    f4 a2 = __builtin_nontemporal_load(&ea4[(size_t)p2.y * 32 + c]);
    f4 a3 = __builtin_nontemporal_load(&ea4[(size_t)p3.y * 32 + c]);
    u16x4 u0 = xb4[(size_t)p0.x * 32 + c];
    u16x4 u1 = xb4[(size_t)p1.x * 32 + c];
    u16x4 u2 = xb4[(size_t)p2.x * 32 + c];
    u16x4 u3 = xb4[(size_t)p3.x * 32 + c];
    acc.x += (a0.x + bf2f(u0.x)) + (a1.x + bf2f(u1.x));
    acc.y += (a0.y + bf2f(u0.y)) + (a1.y + bf2f(u1.y));
    acc.z += (a0.z + bf2f(u0.z)) + (a1.z + bf2f(u1.z));
    acc.w += (a0.w + bf2f(u0.w)) + (a1.w + bf2f(u1.w));
    acc.x += (a2.x + bf2f(u2.x)) + (a3.x + bf2f(u3.x));
    acc.y += (a2.y + bf2f(u2.y)) + (a3.y + bf2f(u3.y));
    acc.z += (a2.z + bf2f(u2.z)) + (a3.z + bf2f(u3.z));
    acc.w += (a2.w + bf2f(u2.w)) + (a3.w + bf2f(u3.w));
  }
  for (; k < e; ++k) {
    i2 p0 = __builtin_nontemporal_load(&csr[k]);
    f4 a0 = __builtin_nontemporal_load(&ea4[(size_t)p0.y * 32 + c]);
    u16x4 u0 = xb4[(size_t)p0.x * 32 + c];
    acc.x += a0.x + bf2f(u0.x);
    acc.y += a0.y + bf2f(u0.y);
    acc.z += a0.z + bf2f(u0.z);
    acc.w += a0.w + bf2f(u0.w);
  }
  u16x4 o;
  o.x = f2bf(acc.x);
  o.y = f2bf(acc.y);
  o.z = f2bf(acc.z);
  o.w = f2bf(acc.w);
  __builtin_nontemporal_store(o, &((u16x4*)yb)[(size_t)n * 32 + c]);
}

// ---------------- exclusive scan of graph sizes -> gstart ----------------
__global__ void scan_kernel(const int* __restrict__ ncount, int* __restrict__ gstart) {
  __shared__ int a[NG];
  int tx = threadIdx.x;
  int v = ncount[tx];
  a[tx] = v;
  __syncthreads();
  for (int off = 1; off < NG; off <<= 1) {
    int u = (tx >= off) ? a[tx - off] : 0;
    __syncthreads();
    a[tx] += u;
    __syncthreads();
  }
  gstart[tx] = a[tx] - v;
  if (tx == NG - 1) gstart[NG] = a[tx];
}

// ---------------- per-graph stable ranks: primary -> p, cond -> ~p ----------------
__global__ __launch_bounds__(256) void rank_kernel(const int* __restrict__ primary,
                                                   const int* __restrict__ gstart,
                                                   const int* __restrict__ ccnt,
                                                   int* __restrict__ pos) {
  int g = blockIdx.x;
  int s = gstart[g], e = gstart[g + 1];
  int pcnt = (e - s) - ccnt[g];
  __shared__ int wcntP[4], wcntC[4];
  int prun = 0, crun = 0;
  for (int i0 = s; i0 < e; i0 += 256) {
    int n = i0 + threadIdx.x;
    bool valid = n < e;
    int isP = (valid && primary[n] == 1) ? 1 : 0;
    int isC = (valid && primary[n] != 1) ? 1 : 0;
    unsigned long long mP = __ballot(isP);
    unsigned long long mC = __ballot(isC);
    int lane = threadIdx.x & 63;
    int wid = threadIdx.x >> 6;
    if (lane == 0) { wcntP[wid] = __popcll(mP); wcntC[wid] = __popcll(mC); }
    __syncthreads();
    int preP = __popcll(mP & ((1ULL << lane) - 1ULL));
    int preC = __popcll(mC & ((1ULL << lane) - 1ULL));
    int woffP = 0, woffC = 0;
#pragma unroll
    for (int ww = 0; ww < 4; ++ww)
      if (ww < wid) { woffP += wcntP[ww]; woffC += wcntC[ww]; }
    int totP = wcntP[0] + wcntP[1] + wcntP[2] + wcntP[3];
    int totC = wcntC[0] + wcntC[1] + wcntC[2] + wcntC[3];
    if (valid) {
      if (isP)
        pos[n] = s + prun + woffP + preP;
      else
        pos[n] = ~(s + pcnt + crun + woffC + preC);
    }
    prun += totP;
    crun += totC;
    __syncthreads();
  }
}

// ---------------- MFMA MLP: writes out rows directly + fused cond-pool sum ----------------
// 256 threads = 4 waves; wave w computes 16 rows; block = 64 rows.
// primary rows: left half = h; cond rows: full zero row. Right half of primary
// rows is filled by poolwrite_kernel afterwards.
__global__ __launch_bounds__(256) void mlp_mfma_kernel(
    const ushort* __restrict__ yb, float* __restrict__ out,
    const ushort* __restrict__ W1T, const float* __restrict__ b1,
    const ushort* __restrict__ W2T, const float* __restrict__ b2,
    const int* __restrict__ batch, const int* __restrict__ primary,
    const int* __restrict__ pos, float* __restrict__ csum, int N) {
  __shared__ ushort tl[4][16][D];  // per-wave relu(t) tile, XOR-swizzled cols
  __shared__ float csl[4][D];      // local csum for up to 4 graphs
  const int tid = threadIdx.x;
  const int w = tid >> 6;
  const int l = tid & 63;
  const int lr = l & 15;
  const int lg = l >> 4;
  const int base = blockIdx.x * 64;
  const int m0 = base + w * 16;

  for (int i = tid; i < 4 * D; i += 256) ((float*)csl)[i] = 0.f;
  int gmin = batch[base < N ? base : N - 1];
  __syncthreads();

  // ---- GEMM1: t = relu(y @ W1 + b1) ----
  f32x4 acc[8];
#pragma unroll
  for (int t = 0; t < 8; ++t) {
    float bv = b1[t * 16 + lr];
    acc[t][0] = bv; acc[t][1] = bv; acc[t][2] = bv; acc[t][3] = bv;
  }
  int arow = m0 + lr;
  if (arow >= N) arow = N - 1;
#pragma unroll
  for (int kk = 0; kk < 4; ++kk) {
    bf16x8 a = *(const bf16x8*)&yb[(size_t)arow * D + kk * 32 + lg * 8];
#pragma unroll
    for (int t = 0; t < 8; ++t) {
      bf16x8 b = *(const bf16x8*)&W1T[(size_t)(t * 16 + lr) * D + kk * 32 + lg * 8];
      acc[t] = __builtin_amdgcn_mfma_f32_16x16x32_bf16(a, b, acc[t], 0, 0, 0);
    }
  }
  // relu + cvt + store to per-wave LDS tile ([m][n], col ^= (m&7)<<3)
#pragma unroll
  for (int t = 0; t < 8; ++t) {
#pragma unroll
    for (int r = 0; r < 4; ++r) {
      float v = acc[t][r];
      v = v > 0.f ? v : 0.f;
      int m = lg * 4 + r;
      int col = (t * 16 + lr) ^ ((m & 7) << 3);
      tl[w][m][col] = f2bf(v);
    }
  }
  __syncthreads();

  // ---- GEMM2: h = t @ W2 + b2 ----
  f32x4 acc2[8];
#pragma unroll
  for (int t = 0; t < 8; ++t) {
    float bv = b2[t * 16 + lr];
    acc2[t][0] = bv; acc2[t][1] = bv; acc2[t][2] = bv; acc2[t][3] = bv;
  }
#pragma unroll
  for (int kk = 0; kk < 4; ++kk) {
    bf16x8 a = *(const bf16x8*)&tl[w][lr][(kk * 32 + lg * 8) ^ ((lr & 7) << 3)];
#pragma unroll
    for (int t = 0; t < 8; ++t) {
      bf16x8 b = *(const bf16x8*)&W2T[(size_t)(t * 16 + lr) * D + kk * 32 + lg * 8];
      acc2[t] = __builtin_amdgcn_mfma_f32_16x16x32_bf16(a, b, acc2[t], 0, 0, 0);
    }
  }

  // ---- epilogue: direct out-row writes + cond-pool accumulation ----
#pragma unroll
  for (int r = 0; r < 4; ++r) {
    int m = m0 + lg * 4 + r;
    if (m >= N) continue;
    int p = pos[m];
    if (p >= 0) {  // primary: left half = h
      size_t ro = (size_t)p * 256;
#pragma unroll
      for (int t = 0; t < 8; ++t)
        __builtin_nontemporal_store(acc2[t][r], &out[ro + t * 16 + lr]);
    } else {  // cond: zero full row, accumulate into pool sum
      size_t ro = (size_t)(~p) * 256;
#pragma unroll
      for (int t = 0; t < 8; ++t) {
        __builtin_nontemporal_store(0.0f, &out[ro + t * 16 + lr]);
        __builtin_nontemporal_store(0.0f, &out[ro + 128 + t * 16 + lr]);
      }
      int g = batch[m];
      int gl = g - gmin;
      if (gl < 4) {
#pragma unroll
        for (int t = 0; t < 8; ++t) atomicAdd(&csl[gl][t * 16 + lr], acc2[t][r]);
      } else {
#pragma unroll
        for (int t = 0; t < 8; ++t)
          unsafeAtomicAdd(&csum[(size_t)g * D + t * 16 + lr], acc2[t][r]);
      }
    }
  }
  __syncthreads();
  for (int i = tid; i < 4 * D; i += 256) {
    float v = ((float*)csl)[i];
    if (v != 0.f) {
      int gl = i >> 7, c = i & 127;
      unsafeAtomicAdd(&csum[(size_t)(gmin + gl) * D + c], v);
    }
  }
}

// ---------------- right half of primary rows: out[p][128+c] = csum[g][c]/cnt ----------------
__global__ __launch_bounds__(256) void poolwrite_kernel(const float* __restrict__ csum,
                                                        const int* __restrict__ ccnt,
                                                        const int* __restrict__ batch,
                                                        const int* __restrict__ pos,
                                                        float* __restrict__ out, int N) {
  long long tid = (long long)blockIdx.x * blockDim.x + threadIdx.x;
  int n = (int)(tid >> 5);
  int c = (int)(tid & 31);
  if (n >= N) return;
  int p = pos[n];
  if (p < 0) return;
  int g = batch[n];
  int cnt = ccnt[g];
  f4 v = {0.f, 0.f, 0.f, 0.f};
  if (cnt > 0) {
    f4 s4 = ((const f4*)csum)[(size_t)g * 32 + c];
    float inv = 1.0f / (float)cnt;
    v = s4 * inv;
  }
  __builtin_nontemporal_store(v, &((f4*)out)[(size_t)p * 64 + 32 + c]);
}

extern "C" void kernel_launch(void* const* d_in, const int* in_sizes, int n_in,
                              void* d_out, int out_size, void* d_ws, size_t ws_size,
                              hipStream_t stream) {
  const float* x = (const float*)d_in[0];
  const int* ei = (const int*)d_in[1];
  const float* ea = (const float*)d_in[2];
  const int* batch = (const int*)d_in[3];
  const int* primary = (const int*)d_in[4];
  const float* W1 = (const float*)d_in[5];
  const float* b1 = (const float*)d_in[6];
  const float* W2 = (const float*)d_in[7];
  const float* b2 = (const float*)d_in[8];
  float* out = (float*)d_out;

  const int N = in_sizes[0] / D;  // 100000
  const int E = in_sizes[1] / 2;  // 1600000
  const int nb = (N + 1023) / 1024;

  // workspace layout
  float* csum = (float*)d_ws;                        // NG*D
  ushort* yb = (ushort*)(csum + (size_t)NG * D);     // N*D bf16
  ushort* xb = yb + (size_t)N * D;                   // N*D bf16
  ushort* W1T = xb + (size_t)N * D;                  // 128*128 bf16
  ushort* W2T = W1T + D * D;                         // 128*128 bf16
  i2* csr = (i2*)(W2T + D * D);                      // E int2
  int* ip = (int*)(csr + (size_t)E);
  int* deg = ip;                                     // N
  int* off = deg + N;                                // N+1 (pad 4)
  int* cursor = off + N + 4;                         // N
  int* bsum = cursor + N;                            // nb (pad 128)
  int* ccnt = bsum + 128;                            // NG
  int* ncount = ccnt + NG;                           // NG
  int* gstart = ncount + NG;                         // NG+1 (pad 260)
  int* pos = gstart + 260;                           // N

  hipMemsetAsync(csum, 0, (size_t)NG * D * 4, stream);
  hipMemsetAsync(deg, 0, (size_t)N * 4, stream);
  hipMemsetAsync(cursor, 0, (size_t)N * 4, stream);
  hipMemsetAsync(ccnt, 0, (size_t)NG * 2 * 4, stream);  // ccnt + ncount contiguous

  deg_counts_kernel<<<(E + 255) / 256, 256, 0, stream>>>(ei, deg, batch, primary, ncount, ccnt,
                                                         E, N);
  scan_block_sums<<<nb, 256, 0, stream>>>(deg, bsum, N);
  scan_bsum<<<1, 64, 0, stream>>>(bsum, nb);
  scan_final<<<nb, 256, 0, stream>>>(deg, bsum, off, N);
  fill_kernel<<<(E + 255) / 256, 256, 0, stream>>>(ei, off, cursor, csr, E);
  cvt_kernel<<<((N * D / 4) + 255) / 256, 256, 0, stream>>>(x, xb, W1, W2, W1T, W2T, N * D / 4);
  {
    long long threads = (long long)N * 32;
    gather_kernel<<<(int)((threads + 255) / 256), 256, 0, stream>>>(xb, ea, csr, off, yb, N);
  }
  scan_kernel<<<1, NG, 0, stream>>>(ncount, gstart);
  rank_kernel<<<NG, 256, 0, stream>>>(primary, gstart, ccnt, pos);
  mlp_mfma_kernel<<<(N + 63) / 64, 256, 0, stream>>>(yb, out, W1T, b1, W2T, b2, batch, primary,
                                                     pos, csum, N);
  poolwrite_kernel<<<(int)(((long long)N * 32 + 255) / 256), 256, 0, stream>>>(csum, ccnt, batch,
                                                                               pos, out, N);
}

// Round 6
// 632.330 us; speedup vs baseline: 5.3144x; 1.0251x over previous
//
#include <hip/hip_runtime.h>

#define D 128
#define NG 256

typedef __attribute__((ext_vector_type(8))) short bf16x8;
typedef __attribute__((ext_vector_type(4))) float f32x4;
typedef __attribute__((ext_vector_type(4))) float f4;
typedef __attribute__((ext_vector_type(2))) int i2;
typedef __attribute__((ext_vector_type(4))) ushort u16x4;

__device__ inline ushort f2bf(float f) {
  uint b = __float_as_uint(f);
  return (ushort)((b + 0x7fffu + ((b >> 16) & 1u)) >> 16);
}
__device__ inline float bf2f(ushort u) { return __uint_as_float((uint)u << 16); }

// ---------------- deg histogram + per-graph counts (fused) ----------------
__global__ __launch_bounds__(256) void deg_counts_kernel(const int* __restrict__ ei,
                                                         int* __restrict__ deg,
                                                         const int* __restrict__ batch,
                                                         const int* __restrict__ primary,
                                                         int* __restrict__ ncount,
                                                         int* __restrict__ ccnt, int E, int N) {
  int e = blockIdx.x * blockDim.x + threadIdx.x;
  if (e < E) {
    int d = ei[E + e];
    atomicAdd(&deg[d], 1);
  }
  if (e < N) {
    int g = batch[e];
    atomicAdd(&ncount[g], 1);
    if (primary[e] == 0) atomicAdd(&ccnt[g], 1);
  }
}

// ---------------- scan over N (3-phase) ----------------
__global__ __launch_bounds__(256) void scan_block_sums(const int* __restrict__ deg,
                                                       int* __restrict__ bsum, int N) {
  __shared__ int red[256];
  int t = threadIdx.x;
  int base = blockIdx.x * 1024;
  int s = 0;
#pragma unroll
  for (int j = 0; j < 4; ++j) {
    int i = base + t * 4 + j;
    if (i < N) s += deg[i];
  }
  red[t] = s;
  __syncthreads();
  for (int o = 128; o > 0; o >>= 1) {
    if (t < o) red[t] += red[t + o];
    __syncthreads();
  }
  if (t == 0) bsum[blockIdx.x] = red[0];
}

__global__ void scan_bsum(int* __restrict__ bsum, int nb) {
  if (threadIdx.x == 0) {
    int run = 0;
    for (int i = 0; i < nb; ++i) {
      int v = bsum[i];
      bsum[i] = run;
      run += v;
    }
  }
}

__global__ __launch_bounds__(256) void scan_final(const int* __restrict__ deg,
                                                  const int* __restrict__ bsum,
                                                  int* __restrict__ off, int N) {
  __shared__ int ts[256];
  int t = threadIdx.x;
  int base = blockIdx.x * 1024;
  int v[4];
  int s = 0;
#pragma unroll
  for (int j = 0; j < 4; ++j) {
    int i = base + t * 4 + j;
    v[j] = (i < N) ? deg[i] : 0;
    s += v[j];
  }
  ts[t] = s;
  __syncthreads();
  for (int o = 1; o < 256; o <<= 1) {
    int u = (t >= o) ? ts[t - o] : 0;
    __syncthreads();
    ts[t] += u;
    __syncthreads();
  }
  int excl = ts[t] - s + bsum[blockIdx.x];
#pragma unroll
  for (int j = 0; j < 4; ++j) {
    int i = base + t * 4 + j;
    if (i < N) off[i] = excl;
    excl += v[j];
    if (i == N - 1) off[N] = excl;
  }
}

// ---------------- CSR fill: csr[off[dst]+slot] = (src, e)  (plain stores: re-read soon) ----
__global__ __launch_bounds__(256) void fill_kernel(const int* __restrict__ ei,
                                                   const int* __restrict__ off,
                                                   int* __restrict__ cursor,
                                                   i2* __restrict__ csr, int E) {
  int e = blockIdx.x * blockDim.x + threadIdx.x;
  if (e >= E) return;
  int s = ei[e];
  int d = ei[E + e];
  int slot = atomicAdd(&cursor[d], 1);
  i2 v;
  v.x = s;
  v.y = e;
  csr[off[d] + slot] = v;
}

// ---------------- x -> bf16 (RNE) + W -> transposed bf16 (fused) ----------------
__global__ __launch_bounds__(256) void cvt_kernel(const float* __restrict__ x,
                                                  ushort* __restrict__ xb,
                                                  const float* __restrict__ W1,
                                                  const float* __restrict__ W2,
                                                  ushort* __restrict__ W1T,
                                                  ushort* __restrict__ W2T, int total4) {
  int i = blockIdx.x * blockDim.x + threadIdx.x;
  if (i < total4) {
    f4 v = __builtin_nontemporal_load(&((const f4*)x)[i]);
    u16x4 o;
    o.x = f2bf(v.x);
    o.y = f2bf(v.y);
    o.z = f2bf(v.z);
    o.w = f2bf(v.w);
    ((u16x4*)xb)[i] = o;
  }
  if (i < 2 * D * D) {
    int w = i >> 14;
    int k = (i >> 7) & 127;
    int n = i & 127;
    const float* src = w ? W2 : W1;
    ushort* dst = w ? W2T : W1T;
    dst[n * 128 + k] = f2bf(src[k * 128 + n]);
  }
}

// ---------------- exclusive scan of graph sizes -> gstart ----------------
__global__ void scan_kernel(const int* __restrict__ ncount, int* __restrict__ gstart) {
  __shared__ int a[NG];
  int tx = threadIdx.x;
  int v = ncount[tx];
  a[tx] = v;
  __syncthreads();
  for (int off = 1; off < NG; off <<= 1) {
    int u = (tx >= off) ? a[tx - off] : 0;
    __syncthreads();
    a[tx] += u;
    __syncthreads();
  }
  gstart[tx] = a[tx] - v;
  if (tx == NG - 1) gstart[NG] = a[tx];
}

// ---------------- per-graph stable ranks: primary -> p, cond -> ~p ----------------
__global__ __launch_bounds__(256) void rank_kernel(const int* __restrict__ primary,
                                                   const int* __restrict__ gstart,
                                                   const int* __restrict__ ccnt,
                                                   int* __restrict__ pos) {
  int g = blockIdx.x;
  int s = gstart[g], e = gstart[g + 1];
  int pcnt = (e - s) - ccnt[g];
  __shared__ int wcntP[4], wcntC[4];
  int prun = 0, crun = 0;
  for (int i0 = s; i0 < e; i0 += 256) {
    int n = i0 + threadIdx.x;
    bool valid = n < e;
    int isP = (valid && primary[n] == 1) ? 1 : 0;
    int isC = (valid && primary[n] != 1) ? 1 : 0;
    unsigned long long mP = __ballot(isP);
    unsigned long long mC = __ballot(isC);
    int lane = threadIdx.x & 63;
    int wid = threadIdx.x >> 6;
    if (lane == 0) { wcntP[wid] = __popcll(mP); wcntC[wid] = __popcll(mC); }
    __syncthreads();
    int preP = __popcll(mP & ((1ULL << lane) - 1ULL));
    int preC = __popcll(mC & ((1ULL << lane) - 1ULL));
    int woffP = 0, woffC = 0;
#pragma unroll
    for (int ww = 0; ww < 4; ++ww)
      if (ww < wid) { woffP += wcntP[ww]; woffC += wcntC[ww]; }
    int totP = wcntP[0] + wcntP[1] + wcntP[2] + wcntP[3];
    int totC = wcntC[0] + wcntC[1] + wcntC[2] + wcntC[3];
    if (valid) {
      if (isP)
        pos[n] = s + prun + woffP + preP;
      else
        pos[n] = ~(s + pcnt + crun + woffC + preC);
    }
    prun += totP;
    crun += totC;
    __syncthreads();
  }
}

// ---------------- FUSED gather + MFMA MLP ----------------
// Block = 256 threads = 4 waves, owns 64 node rows.
// Phase A: 8 groups x 32 lanes gather y rows into swizzled LDS tile.
// Phase B: MFMA MLP (h = relu(y@W1+b1)@W2+b2) reading A-frags from LDS;
//          epilogue writes output rows via pos + cond-pool accumulation.
__global__ __launch_bounds__(256, 4) void fused_gather_mlp_kernel(
    const ushort* __restrict__ xb, const float* __restrict__ ea,
    const i2* __restrict__ csr, const int* __restrict__ off, float* __restrict__ out,
    const ushort* __restrict__ W1T, const float* __restrict__ b1,
    const ushort* __restrict__ W2T, const float* __restrict__ b2,
    const int* __restrict__ batch, const int* __restrict__ primary,
    const int* __restrict__ pos, float* __restrict__ csum, int N) {
  __shared__ ushort ylds[64][D];    // swizzled: byte ^= (row&7)<<4
  __shared__ ushort tl[4][16][D];   // per-wave relu(t) tile, XOR-swizzled cols
  __shared__ float csl[4][D];       // local csum for up to 4 graphs
  const int tid = threadIdx.x;
  const int base = blockIdx.x * 64;

  for (int i = tid; i < 4 * D; i += 256) ((float*)csl)[i] = 0.f;
  const int gmin = batch[base < N ? base : N - 1];

  // ---- Phase A: gather 8 rows per 32-lane group ----
  {
    const int gid = tid >> 5;
    const int c = tid & 31;
    const f4* ea4 = (const f4*)ea;
    const u16x4* xb4 = (const u16x4*)xb;
    for (int i = 0; i < 8; ++i) {
      const int m = gid * 8 + i;
      const int n = base + m;
      f4 acc = {0.f, 0.f, 0.f, 0.f};
      if (n < N) {
        u16x4 self = xb4[(size_t)n * 32 + c];
        acc.x = bf2f(self.x);
        acc.y = bf2f(self.y);
        acc.z = bf2f(self.z);
        acc.w = bf2f(self.w);
        int s = off[n], e = off[n + 1];
        int k = s;
        for (; k + 4 <= e; k += 4) {
          i2 p0 = csr[k];
          i2 p1 = csr[k + 1];
          i2 p2 = csr[k + 2];
          i2 p3 = csr[k + 3];
          f4 a0 = __builtin_nontemporal_load(&ea4[(size_t)p0.y * 32 + c]);
          f4 a1 = __builtin_nontemporal_load(&ea4[(size_t)p1.y * 32 + c]);
          f4 a2 = __builtin_nontemporal_load(&ea4[(size_t)p2.y * 32 + c]);
          f4 a3 = __builtin_nontemporal_load(&ea4[(size_t)p3.y * 32 + c]);
          u16x4 u0 = xb4[(size_t)p0.x * 32 + c];
          u16x4 u1 = xb4[(size_t)p1.x * 32 + c];
          u16x4 u2 = xb4[(size_t)p2.x * 32 + c];
          u16x4 u3 = xb4[(size_t)p3.x * 32 + c];
          acc.x += (a0.x + bf2f(u0.x)) + (a1.x + bf2f(u1.x));
          acc.y += (a0.y + bf2f(u0.y)) + (a1.y + bf2f(u1.y));
          acc.z += (a0.z + bf2f(u0.z)) + (a1.z + bf2f(u1.z));
          acc.w += (a0.w + bf2f(u0.w)) + (a1.w + bf2f(u1.w));
          acc.x += (a2.x + bf2f(u2.x)) + (a3.x + bf2f(u3.x));
          acc.y += (a2.y + bf2f(u2.y)) + (a3.y + bf2f(u3.y));
          acc.z += (a2.z + bf2f(u2.z)) + (a3.z + bf2f(u3.z));
          acc.w += (a2.w + bf2f(u2.w)) + (a3.w + bf2f(u3.w));
        }
        for (; k < e; ++k) {
          i2 p0 = csr[k];
          f4 a0 = __builtin_nontemporal_load(&ea4[(size_t)p0.y * 32 + c]);
          u16x4 u0 = xb4[(size_t)p0.x * 32 + c];
          acc.x += a0.x + bf2f(u0.x);
          acc.y += a0.y + bf2f(u0.y);
          acc.z += a0.z + bf2f(u0.z);
          acc.w += a0.w + bf2f(u0.w);
        }
      }
      u16x4 o;
      o.x = f2bf(acc.x);
      o.y = f2bf(acc.y);
      o.z = f2bf(acc.z);
      o.w = f2bf(acc.w);
      *(u16x4*)((char*)&ylds[m][0] + ((c * 8) ^ (i << 4))) = o;  // (m&7)==i
    }
  }
  __syncthreads();

  // ---- Phase B: MFMA MLP ----
  const int w = tid >> 6;
  const int l = tid & 63;
  const int lr = l & 15;
  const int lg = l >> 4;
  const int m0 = base + w * 16;

  // GEMM1: t = relu(y @ W1 + b1)
  f32x4 acc[8];
#pragma unroll
  for (int t = 0; t < 8; ++t) {
    float bv = b1[t * 16 + lr];
    acc[t][0] = bv; acc[t][1] = bv; acc[t][2] = bv; acc[t][3] = bv;
  }
  const char* arow_base = (const char*)&ylds[w * 16 + lr][0];
  const int arow_swz = (lr & 7) << 4;
#pragma unroll
  for (int kk = 0; kk < 4; ++kk) {
    bf16x8 a = *(const bf16x8*)(arow_base + ((kk * 64 + lg * 16) ^ arow_swz));
#pragma unroll
    for (int t = 0; t < 8; ++t) {
      bf16x8 b = *(const bf16x8*)&W1T[(size_t)(t * 16 + lr) * D + kk * 32 + lg * 8];
      acc[t] = __builtin_amdgcn_mfma_f32_16x16x32_bf16(a, b, acc[t], 0, 0, 0);
    }
  }
  // relu + cvt + store to per-wave LDS tile ([m][n], col ^= (m&7)<<3)
#pragma unroll
  for (int t = 0; t < 8; ++t) {
#pragma unroll
    for (int r = 0; r < 4; ++r) {
      float v = acc[t][r];
      v = v > 0.f ? v : 0.f;
      int m = lg * 4 + r;
      int col = (t * 16 + lr) ^ ((m & 7) << 3);
      tl[w][m][col] = f2bf(v);
    }
  }
  __syncthreads();

  // GEMM2: h = t @ W2 + b2
  f32x4 acc2[8];
#pragma unroll
  for (int t = 0; t < 8; ++t) {
    float bv = b2[t * 16 + lr];
    acc2[t][0] = bv; acc2[t][1] = bv; acc2[t][2] = bv; acc2[t][3] = bv;
  }
#pragma unroll
  for (int kk = 0; kk < 4; ++kk) {
    bf16x8 a = *(const bf16x8*)&tl[w][lr][(kk * 32 + lg * 8) ^ ((lr & 7) << 3)];
#pragma unroll
    for (int t = 0; t < 8; ++t) {
      bf16x8 b = *(const bf16x8*)&W2T[(size_t)(t * 16 + lr) * D + kk * 32 + lg * 8];
      acc2[t] = __builtin_amdgcn_mfma_f32_16x16x32_bf16(a, b, acc2[t], 0, 0, 0);
    }
  }

  // epilogue: direct out-row writes + cond-pool accumulation
#pragma unroll
  for (int r = 0; r < 4; ++r) {
    int m = m0 + lg * 4 + r;
    if (m >= N) continue;
    int p = pos[m];
    if (p >= 0) {  // primary: left half = h
      size_t ro = (size_t)p * 256;
#pragma unroll
      for (int t = 0; t < 8; ++t)
        __builtin_nontemporal_store(acc2[t][r], &out[ro + t * 16 + lr]);
    } else {  // cond: zero full row, accumulate into pool sum
      size_t ro = (size_t)(~p) * 256;
#pragma unroll
      for (int t = 0; t < 8; ++t) {
        __builtin_nontemporal_store(0.0f, &out[ro + t * 16 + lr]);
        __builtin_nontemporal_store(0.0f, &out[ro + 128 + t * 16 + lr]);
      }
      int g = batch[m];
      int gl = g - gmin;
      if (gl < 4) {
#pragma unroll
        for (int t = 0; t < 8; ++t) atomicAdd(&csl[gl][t * 16 + lr], acc2[t][r]);
      } else {
#pragma unroll
        for (int t = 0; t < 8; ++t)
          unsafeAtomicAdd(&csum[(size_t)g * D + t * 16 + lr], acc2[t][r]);
      }
    }
  }
  __syncthreads();
  for (int i = tid; i < 4 * D; i += 256) {
    float v = ((float*)csl)[i];
    if (v != 0.f) {
      int gl = i >> 7, c = i & 127;
      unsafeAtomicAdd(&csum[(size_t)(gmin + gl) * D + c], v);
    }
  }
}

// ---------------- right half of primary rows: out[p][128+c] = csum[g][c]/cnt ----------------
__global__ __launch_bounds__(256) void poolwrite_kernel(const float* __restrict__ csum,
                                                        const int* __restrict__ ccnt,
                                                        const int* __restrict__ batch,
                                                        const int* __restrict__ pos,
                                                        float* __restrict__ out, int N) {
  long long tid = (long long)blockIdx.x * blockDim.x + threadIdx.x;
  int n = (int)(tid >> 5);
  int c = (int)(tid & 31);
  if (n >= N) return;
  int p = pos[n];
  if (p < 0) return;
  int g = batch[n];
  int cnt = ccnt[g];
  f4 v = {0.f, 0.f, 0.f, 0.f};
  if (cnt > 0) {
    f4 s4 = ((const f4*)csum)[(size_t)g * 32 + c];
    float inv = 1.0f / (float)cnt;
    v = s4 * inv;
  }
  __builtin_nontemporal_store(v, &((f4*)out)[(size_t)p * 64 + 32 + c]);
}

extern "C" void kernel_launch(void* const* d_in, const int* in_sizes, int n_in,
                              void* d_out, int out_size, void* d_ws, size_t ws_size,
                              hipStream_t stream) {
  const float* x = (const float*)d_in[0];
  const int* ei = (const int*)d_in[1];
  const float* ea = (const float*)d_in[2];
  const int* batch = (const int*)d_in[3];
  const int* primary = (const int*)d_in[4];
  const float* W1 = (const float*)d_in[5];
  const float* b1 = (const float*)d_in[6];
  const float* W2 = (const float*)d_in[7];
  const float* b2 = (const float*)d_in[8];
  float* out = (float*)d_out;

  const int N = in_sizes[0] / D;  // 100000
  const int E = in_sizes[1] / 2;  // 1600000
  const int nb = (N + 1023) / 1024;

  // workspace layout
  float* csum = (float*)d_ws;                        // NG*D
  ushort* xb = (ushort*)(csum + (size_t)NG * D);     // N*D bf16
  ushort* W1T = xb + (size_t)N * D;                  // 128*128 bf16
  ushort* W2T = W1T + D * D;                         // 128*128 bf16
  i2* csr = (i2*)(W2T + D * D);                      // E int2
  int* ip = (int*)(csr + (size_t)E);
  int* deg = ip;                                     // N
  int* off = deg + N;                                // N+1 (pad 4)
  int* cursor = off + N + 4;                         // N
  int* bsum = cursor + N;                            // nb (pad 128)
  int* ccnt = bsum + 128;                            // NG
  int* ncount = ccnt + NG;                           // NG
  int* gstart = ncount + NG;                         // NG+1 (pad 260)
  int* pos = gstart + 260;                           // N

  hipMemsetAsync(csum, 0, (size_t)NG * D * 4, stream);
  hipMemsetAsync(deg, 0, (size_t)N * 4, stream);
  hipMemsetAsync(cursor, 0, (size_t)N * 4, stream);
  hipMemsetAsync(ccnt, 0, (size_t)NG * 2 * 4, stream);  // ccnt + ncount contiguous

  deg_counts_kernel<<<(E + 255) / 256, 256, 0, stream>>>(ei, deg, batch, primary, ncount, ccnt,
                                                         E, N);
  scan_block_sums<<<nb, 256, 0, stream>>>(deg, bsum, N);
  scan_bsum<<<1, 64, 0, stream>>>(bsum, nb);
  scan_final<<<nb, 256, 0, stream>>>(deg, bsum, off, N);
  fill_kernel<<<(E + 255) / 256, 256, 0, stream>>>(ei, off, cursor, csr, E);
  cvt_kernel<<<((N * D / 4) + 255) / 256, 256, 0, stream>>>(x, xb, W1, W2, W1T, W2T, N * D / 4);
  scan_kernel<<<1, NG, 0, stream>>>(ncount, gstart);
  rank_kernel<<<NG, 256, 0, stream>>>(primary, gstart, ccnt, pos);
  fused_gather_mlp_kernel<<<(N + 63) / 64, 256, 0, stream>>>(xb, ea, csr, off, out, W1T, b1,
                                                             W2T, b2, batch, primary, pos,
                                                             csum, N);
  poolwrite_kernel<<<(int)(((long long)N * 32 + 255) / 256), 256, 0, stream>>>(csum, ccnt, batch,
                                                                               pos, out, N);
}